// Round 15
// baseline (215.280 us; speedup 1.0000x reference)
//
#include <hip/hip_runtime.h>
#include <hip/hip_bf16.h>

typedef unsigned short u16;
typedef __bf16 bf16x8 __attribute__((ext_vector_type(8)));
typedef float f32x4 __attribute__((ext_vector_type(4)));

#define BATCH 16
#define C 256
#define NTOK 4096      // H*W
#define CN 1048576     // C*NTOK

__device__ __forceinline__ u16 f2b(float f) {
  __hip_bfloat16 h = __float2bfloat16(f);
  return __builtin_bit_cast(u16, h);
}
__device__ __forceinline__ float b2f(u16 u) {
  unsigned int x = ((unsigned int)u) << 16;
  return __builtin_bit_cast(float, x);
}

// async global->LDS, 16B per lane. LDS dest must be wave-uniform base
// (HW adds lane*16); global src is per-lane.
__device__ __forceinline__ void glds16(const u16* g, u16* l) {
  __builtin_amdgcn_global_load_lds(
      (const __attribute__((address_space(1))) unsigned int*)(g),
      (__attribute__((address_space(3))) unsigned int*)(l), 16, 0, 0);
}

// ---------------------------------------------------------------------------
// prep_x: x f32 [B][C][N] -> xbf [B][C][N], xT [B][N][C]; row partial sums
// atomically into rws (rws zeroed by prep_w, launched before).
__global__ __launch_bounds__(256) void prep_x_kernel(
    const float* __restrict__ x, u16* __restrict__ xbf, u16* __restrict__ xT,
    float* __restrict__ rws) {
  __shared__ float t[32][33];
  int b = blockIdx.z;
  int c0 = blockIdx.y * 32, n0 = blockIdx.x * 32;
  int tid = threadIdx.x;
  int i = tid >> 3, j4 = (tid & 7) * 4;
  const float* xb = x + (long)b * CN;
  float4 v = *(const float4*)(xb + (long)(c0 + i) * NTOK + n0 + j4);
  ushort4 bv;
  bv.x = f2b(v.x); bv.y = f2b(v.y); bv.z = f2b(v.z); bv.w = f2b(v.w);
  *(ushort4*)(xbf + (long)b * CN + (long)(c0 + i) * NTOK + n0 + j4) = bv;
  t[i][j4 + 0] = v.x; t[i][j4 + 1] = v.y; t[i][j4 + 2] = v.z; t[i][j4 + 3] = v.w;
  __syncthreads();
  ushort4 o;
  o.x = f2b(t[j4 + 0][i]); o.y = f2b(t[j4 + 1][i]);
  o.z = f2b(t[j4 + 2][i]); o.w = f2b(t[j4 + 3][i]);
  *(ushort4*)(xT + (long)b * CN + (long)(n0 + i) * C + c0 + j4) = o;
  if (tid < 32) {
    float s = 0.f;
#pragma unroll
    for (int j = 0; j < 32; ++j) s += t[tid][j];
    atomicAdd(&rws[b * C + c0 + tid], s);
  }
}

// ---------------------------------------------------------------------------
// prep_w: WqT (transposed Wq, for reduceG_T1 matvec), Wk, WvT, Pw, cw.
__global__ __launch_bounds__(256) void prep_w_kernel(
    const float* __restrict__ qkv_w, const float* __restrict__ proj_w,
    const float* __restrict__ conv_w, u16* __restrict__ WqT, u16* __restrict__ Wk,
    u16* __restrict__ WvT, u16* __restrict__ Pw, u16* __restrict__ cw,
    float* __restrict__ rws, u16* __restrict__ zbuf) {
  int idx = blockIdx.x * 256 + threadIdx.x;
  if (idx < 4096) rws[idx] = 0.f;
  if (idx < 256) zbuf[idx] = 0;
  if (idx < 65536) {
    // WqT[k][r] = Wq[r][k]; coalesced read, scattered write
    WqT[(idx & 255) * 256 + (idx >> 8)] = f2b(qkv_w[idx]);
  } else if (idx < 131072) {
    int e = idx - 65536;
    Wk[e] = f2b(qkv_w[65536 + e]);
  } else if (idx < 196608) {
    int e = idx - 131072;
    int i = e >> 8, d = e & 255;
    WvT[e] = f2b(qkv_w[131072 + d * 256 + i]);
  } else if (idx < 262144) {
    int e = idx - 196608;
    Pw[e] = f2b(proj_w[e]);
  } else if (idx < 851968) {
    int e = idx - 262144;
    int o = e / 2304;
    int rem = e - o * 2304;
    int tap = rem >> 8, i = rem & 255;
    cw[e] = f2b(conv_w[o * 2304 + i * 9 + tap]);
  }
}

// ---------------------------------------------------------------------------
// Generic GEMM C = A*B^T (both K-contiguous), 128x128 tile, BK=32, 4 waves,
// global_load_lds staging + slot-XOR swizzle, double-buffered.
// EPI 0: f32 partial store (slice = blockIdx.y of gridDim.y). EPI 1: bf16.
// EPI 2: S-epi. EPI 4: bf16 + extra cbias block at blockIdx.x==4.
template <int EPI>
__global__ __launch_bounds__(256, 2) void gemm_glds_kernel(
    const u16* __restrict__ A, const u16* __restrict__ B, void* __restrict__ Cv,
    int K, int lda, int ldb, int ldc, int tilesN, long sA, long sB, long sC,
    float scale, const float* __restrict__ e1, const float* __restrict__ e2,
    const float* __restrict__ e3, const float* __restrict__ e4, int e34stride) {
  if (EPI == 4 && blockIdx.x == 4) {
    // cbias: cb[b][j] = proj_b[j] + sum_d M[b][j][d]*qkv_b[512+d]
    int bb = blockIdx.z, j = threadIdx.x;
    const u16* m = A + (long)bb * sA + (long)j * 256;
    float s = 0.f;
    for (int d = 0; d < 256; ++d) s += b2f(m[d]) * e1[512 + d];
    float* cbout = const_cast<float*>(e4);
    cbout[bb * 256 + j] = e2[j] + s;
    return;
  }
  int b = blockIdx.z, ks = blockIdx.y;
  A += (long)b * sA + (long)ks * K;
  B += (long)b * sB + (long)ks * K;
  int ty = blockIdx.x / tilesN, tx = blockIdx.x % tilesN;
  int row0 = ty * 128, col0 = tx * 128;

  __shared__ u16 lA[2][4096];
  __shared__ u16 lB[2][4096];

  int tid = threadIdx.x;
  int lane = tid & 63, wv = tid >> 6;
  int wm = wv >> 1, wn = wv & 1;
  int fr = lane & 15, kq = lane >> 4;
  int kqs = kq ^ ((fr >> 1) & 3);

  int c0 = wv * 128 + lane, c1 = c0 + 64;
  int r0s = c0 >> 2, r1s = c1 >> 2;
  int ls0 = (c0 & 3) ^ ((r0s >> 1) & 3);
  int ls1 = (c1 & 3) ^ ((r1s >> 1) & 3);
  const u16* pA0 = A + (long)(row0 + r0s) * lda + ls0 * 8;
  const u16* pA1 = A + (long)(row0 + r1s) * lda + ls1 * 8;
  const u16* pB0 = B + (long)(col0 + r0s) * ldb + ls0 * 8;
  const u16* pB1 = B + (long)(col0 + r1s) * ldb + ls1 * 8;
  int dst0 = wv * 1024, dst1 = wv * 1024 + 512;

  f32x4 acc[4][4] = {};

  auto STAGE = [&](int buf, int t) {
    int k0 = t << 5;
    glds16(pA0 + k0, &lA[buf][dst0]);
    glds16(pA1 + k0, &lA[buf][dst1]);
    glds16(pB0 + k0, &lB[buf][dst0]);
    glds16(pB1 + k0, &lB[buf][dst1]);
  };
  auto COMPUTE = [&](int buf) {
    bf16x8 af[4], bfr[4];
#pragma unroll
    for (int m = 0; m < 4; ++m)
      af[m] = *(const bf16x8*)&lA[buf][(wm * 64 + m * 16 + fr) * 32 + kqs * 8];
#pragma unroll
    for (int n = 0; n < 4; ++n)
      bfr[n] = *(const bf16x8*)&lB[buf][(wn * 64 + n * 16 + fr) * 32 + kqs * 8];
#pragma unroll
    for (int m = 0; m < 4; ++m)
#pragma unroll
      for (int n = 0; n < 4; ++n)
        acc[m][n] = __builtin_amdgcn_mfma_f32_16x16x32_bf16(af[m], bfr[n], acc[m][n], 0, 0, 0);
  };

  int nk = K >> 5, cur = 0;
  STAGE(0, 0);
  __syncthreads();
  for (int t = 0; t < nk; ++t) {
    if (t + 1 < nk) STAGE(cur ^ 1, t + 1);
    COMPUTE(cur);
    __syncthreads();
    cur ^= 1;
  }

  if (EPI == 0) {
    float* Cb = (float*)Cv + ((long)b * gridDim.y + ks) * sC;
#pragma unroll
    for (int m = 0; m < 4; ++m)
#pragma unroll
      for (int n = 0; n < 4; ++n)
#pragma unroll
        for (int r = 0; r < 4; ++r) {
          int gr = row0 + wm * 64 + m * 16 + kq * 4 + r;
          int gc = col0 + wn * 64 + n * 16 + fr;
          Cb[(long)gr * ldc + gc] = acc[m][n][r];
        }
  } else if (EPI == 1 || EPI == 4) {
    __hip_bfloat16* Cb = (__hip_bfloat16*)Cv + (long)b * sC;
#pragma unroll
    for (int m = 0; m < 4; ++m)
#pragma unroll
      for (int n = 0; n < 4; ++n)
#pragma unroll
        for (int r = 0; r < 4; ++r) {
          int gr = row0 + wm * 64 + m * 16 + kq * 4 + r;
          int gc = col0 + wn * 64 + n * 16 + fr;
          Cb[(long)gr * ldc + gc] = __float2bfloat16(acc[m][n][r]);
        }
  } else if (EPI == 2) {
    float* Cb = (float*)Cv + (long)b * sC;
    const float* ub = e3 + (long)b * e34stride;
    const float* wb = e4 + (long)b * e34stride;
#pragma unroll
    for (int m = 0; m < 4; ++m)
#pragma unroll
      for (int n = 0; n < 4; ++n)
#pragma unroll
        for (int r = 0; r < 4; ++r) {
          int gr = row0 + wm * 64 + m * 16 + kq * 4 + r;
          int gc = col0 + wn * 64 + n * 16 + fr;
          float v = acc[m][n][r] + e1[gr] * ub[gc] + e2[gc] * wb[gr] +
                    4096.0f * e1[gr] * e2[gc];
          Cb[(long)gr * ldc + gc] = v * scale;
        }
  }
}

// ---------------------------------------------------------------------------
// reduceG + T1 + bias_uw merged. grid (65, B), nsl = split-K slice count:
// x<64: sum nsl split-K partials of G rows [4x..4x+4) (f32); G symmetric ->
//       T1[c][d] = sum_i Wq[c,i]*G[d,i]; thread c computes 4 T1 columns.
// x==64: u[b][t]=Wk[t,:]*r[b,:], w[b][t]=Wq[t,:]*r[b,:].
__global__ __launch_bounds__(256) void reduceG_T1_bias_kernel(
    const float* __restrict__ Gp, const u16* __restrict__ WqT,
    u16* __restrict__ T1, const float* __restrict__ qkv_w,
    const float* __restrict__ r, float* __restrict__ u, float* __restrict__ w,
    int nsl) {
  int b = blockIdx.y;
  if (blockIdx.x < 64) {
    __shared__ float g[4][256];
    int tid = threadIdx.x;
    int e = blockIdx.x * 1024 + tid * 4;
    const float* base = Gp + (long)b * nsl * 65536;
    float4 s = *(const float4*)(base + e);
    for (int sl = 1; sl < nsl; ++sl) {
      float4 v = *(const float4*)(base + (long)sl * 65536 + e);
      s.x += v.x; s.y += v.y; s.z += v.z; s.w += v.w;
    }
    int rr = tid >> 6, cc = (tid & 63) * 4;
    g[rr][cc + 0] = s.x; g[rr][cc + 1] = s.y;
    g[rr][cc + 2] = s.z; g[rr][cc + 3] = s.w;
    __syncthreads();
    int c = tid;
    float a0 = 0.f, a1 = 0.f, a2 = 0.f, a3 = 0.f;
#pragma unroll 4
    for (int i = 0; i < 256; ++i) {
      float wq = b2f(WqT[i * 256 + c]);
      a0 += wq * g[0][i]; a1 += wq * g[1][i];
      a2 += wq * g[2][i]; a3 += wq * g[3][i];
    }
    ushort4 o;
    o.x = f2b(a0); o.y = f2b(a1); o.z = f2b(a2); o.w = f2b(a3);
    *(ushort4*)(T1 + (long)b * 65536 + (long)c * 256 + blockIdx.x * 4) = o;
  } else {
    int t = threadIdx.x;
    const float* rb = r + b * C;
    float su = 0.f, sw = 0.f;
    for (int i = 0; i < C; ++i) {
      float rv = rb[i];
      su += qkv_w[(256 + t) * 256 + i] * rv;
      sw += qkv_w[t * 256 + i] * rv;
    }
    u[b * C + t] = su;
    w[b * C + t] = sw;
  }
}

// ---------------------------------------------------------------------------
// softmax over rows of S -> attn^T bf16 (attnT[d][c] = attn[c][d])
__global__ __launch_bounds__(256) void softmax_kernel(const float* __restrict__ S,
                                                      u16* __restrict__ attnT) {
  int row = blockIdx.x;
  int t = threadIdx.x;
  float v = S[(long)row * C + t];
  __shared__ float red[256];
  red[t] = v; __syncthreads();
  for (int st = 128; st > 0; st >>= 1) {
    if (t < st) red[t] = fmaxf(red[t], red[t + st]);
    __syncthreads();
  }
  float mx = red[0];
  __syncthreads();
  float e = __expf(v - mx);
  red[t] = e; __syncthreads();
  for (int st = 128; st > 0; st >>= 1) {
    if (t < st) red[t] += red[t + st];
    __syncthreads();
  }
  float inv = 1.0f / red[0];
  int b = row >> 8, c = row & 255;
  attnT[(long)b * 65536 + t * 256 + c] = f2b(e * inv);
}

// ---------------------------------------------------------------------------
// Fused conv3x3 implicit-GEMM + attention-output GEMM, BK=64 (proven:
// 104us, MfmaUtil 36%, 0 bank conflicts). 128x128 tile, 4 waves, acc[4][4];
// merged conv+attn accumulator. 10 taps (9 conv + 1 attn) x 4 chunks of 64-K
// = 40 barrier-steps. 2 LDS buffers [128][64] (64KB -> 2 blocks/CU).
// Slot swizzle: LDS[row][slot] holds global slot (slot ^ (row&7)); read
// applies same XOR. Structure notes: per-wave tiles >64x64 spill (r3/r13:
// VGPR cap ~256 at 2 blocks/CU); A-from-global gathers serialize VMEM (r9);
// BK=32 halves barrier spacing without raising occupancy (r12). This config
// is the measured optimum of the explored space.
__global__ __launch_bounds__(256, 2) void convattn_kernel(
    const u16* __restrict__ xT, const u16* __restrict__ cw,
    const u16* __restrict__ W2, const u16* __restrict__ zbuf,
    const float* __restrict__ conv_b, const float* __restrict__ cb,
    float* __restrict__ out) {
  int b = blockIdx.y;
  int to = blockIdx.x >> 5;  // 0..1
  int tn = blockIdx.x & 31;  // 0..31
  int row0 = to * 128, col0 = tn * 128;
  const u16* xTb = xT + (long)b * CN;
  const u16* W2b = W2 + (long)b * 65536;

  __shared__ u16 lA[2][8192];   // [128][64] u16 per buffer
  __shared__ u16 lB[2][8192];

  int tid = threadIdx.x;
  int lane = tid & 63, w = tid >> 6;
  int wm = w >> 1, wn = w & 1;
  int fr = lane & 15, kq = lane >> 4;
  int fx = fr & 7;              // == row&7 for all fragment rows

  // staging decomp: each wave stages rows [w*32, w*32+32), 4 instrs of 8 rows
  int lr = lane >> 3, sl = lane & 7;
  int ss = sl ^ lr;             // swizzled source slot (row&7 == lr)

  const u16* aA[4]; const u16* pBt[4]; int hh[4], ww[4];
  const u16* zsrc = zbuf + ss * 8;
#pragma unroll
  for (int i = 0; i < 4; ++i) {
    int r = w * 32 + i * 8 + lr;
    aA[i] = cw + (long)(row0 + r) * 2304 + ss * 8;
    int t = col0 + r;
    hh[i] = t >> 6; ww[i] = t & 63;
    pBt[i] = xTb + (long)t * 256 + ss * 8;
  }
  int nb = col0 >> 8, jb = col0 & 255;

  f32x4 acc[4][4] = {};
  const u16 *at0, *at1, *at2, *at3, *bt0, *bt1, *bt2, *bt3;

  auto set_tap = [&](int tap) {
    int dh = tap / 3 - 1, dw = tap % 3 - 1;
    long sh = (long)(dh * 64 + dw) * 256;
    at0 = aA[0] + tap * 256; at1 = aA[1] + tap * 256;
    at2 = aA[2] + tap * 256; at3 = aA[3] + tap * 256;
    bool v0 = ((unsigned)(hh[0] + dh) < 64u) && ((unsigned)(ww[0] + dw) < 64u);
    bool v1 = ((unsigned)(hh[1] + dh) < 64u) && ((unsigned)(ww[1] + dw) < 64u);
    bool v2 = ((unsigned)(hh[2] + dh) < 64u) && ((unsigned)(ww[2] + dw) < 64u);
    bool v3 = ((unsigned)(hh[3] + dh) < 64u) && ((unsigned)(ww[3] + dw) < 64u);
    bt0 = v0 ? pBt[0] + sh : zsrc;
    bt1 = v1 ? pBt[1] + sh : zsrc;
    bt2 = v2 ? pBt[2] + sh : zsrc;
    bt3 = v3 ? pBt[3] + sh : zsrc;
  };
  auto set_attn = [&]() {
#pragma unroll
    for (int i = 0; i < 4; ++i) {
      int r = w * 32 + i * 8 + lr;
      const u16* a = xTb + (long)((row0 + r) * 16 + nb) * 256 + ss * 8;
      const u16* bb = W2b + (long)(jb + r) * 256 + ss * 8;
      if (i == 0) { at0 = a; bt0 = bb; }
      else if (i == 1) { at1 = a; bt1 = bb; }
      else if (i == 2) { at2 = a; bt2 = bb; }
      else { at3 = a; bt3 = bb; }
    }
  };

  auto STAGE = [&](int buf, int chunk) {
    int k = chunk * 64;
    glds16(at0 + k, &lA[buf][(w * 32 + 0) * 64]);
    glds16(at1 + k, &lA[buf][(w * 32 + 8) * 64]);
    glds16(at2 + k, &lA[buf][(w * 32 + 16) * 64]);
    glds16(at3 + k, &lA[buf][(w * 32 + 24) * 64]);
    glds16(bt0 + k, &lB[buf][(w * 32 + 0) * 64]);
    glds16(bt1 + k, &lB[buf][(w * 32 + 8) * 64]);
    glds16(bt2 + k, &lB[buf][(w * 32 + 16) * 64]);
    glds16(bt3 + k, &lB[buf][(w * 32 + 24) * 64]);
  };
  auto COMPUTE = [&](int buf) {
    bf16x8 af[4][2], bf[4][2];
#pragma unroll
    for (int m = 0; m < 4; ++m) {
      int row = wm * 64 + m * 16 + fr;
#pragma unroll
      for (int kh = 0; kh < 2; ++kh)
        af[m][kh] = *(const bf16x8*)&lA[buf][row * 64 + (((kh << 2) + kq) ^ fx) * 8];
    }
#pragma unroll
    for (int n = 0; n < 4; ++n) {
      int row = wn * 64 + n * 16 + fr;
#pragma unroll
      for (int kh = 0; kh < 2; ++kh)
        bf[n][kh] = *(const bf16x8*)&lB[buf][row * 64 + (((kh << 2) + kq) ^ fx) * 8];
    }
    __builtin_amdgcn_s_setprio(1);
#pragma unroll
    for (int kh = 0; kh < 2; ++kh)
#pragma unroll
      for (int m = 0; m < 4; ++m)
#pragma unroll
        for (int n = 0; n < 4; ++n)
          acc[m][n] = __builtin_amdgcn_mfma_f32_16x16x32_bf16(af[m][kh], bf[n][kh], acc[m][n], 0, 0, 0);
    __builtin_amdgcn_s_setprio(0);
  };

  set_tap(0);
  STAGE(0, 0);
  asm volatile("s_waitcnt vmcnt(0)" ::: "memory");
  __builtin_amdgcn_sched_barrier(0);
  __builtin_amdgcn_s_barrier();
  __builtin_amdgcn_sched_barrier(0);

  int buf = 0;
#pragma unroll 1
  for (int T = 0; T < 10; ++T) {
#pragma unroll
    for (int j = 0; j < 4; ++j) {
      if (!(T == 9 && j == 3)) {
        if (j < 3) {
          STAGE(buf ^ 1, j + 1);
        } else {
          if (T < 8) set_tap(T + 1);
          else set_attn();
          STAGE(buf ^ 1, 0);
        }
      }
      COMPUTE(buf);
      asm volatile("s_waitcnt vmcnt(0)" ::: "memory");
      __builtin_amdgcn_sched_barrier(0);
      __builtin_amdgcn_s_barrier();
      __builtin_amdgcn_sched_barrier(0);
      buf ^= 1;
    }
  }

  float* ob = out + (long)b * CN;
  const float* cbb = cb + b * C;
#pragma unroll
  for (int m = 0; m < 4; ++m) {
    int go = row0 + wm * 64 + m * 16 + kq * 4;
#pragma unroll
    for (int nn = 0; nn < 4; ++nn) {
      int cc = wn * 64 + nn * 16 + fr;
      float cbv = cbb[jb + cc];
#pragma unroll
      for (int r = 0; r < 4; ++r)
        ob[(long)(go + r) * NTOK + col0 + cc] =
            acc[m][nn][r] + conv_b[go + r] + cbv;
    }
  }
}

// ---------------------------------------------------------------------------
extern "C" void kernel_launch(void* const* d_in, const int* in_sizes, int n_in,
                              void* d_out, int out_size, void* d_ws, size_t ws_size,
                              hipStream_t stream) {
  const float* x = (const float*)d_in[0];
  const float* qkv_w = (const float*)d_in[1];
  const float* qkv_b = (const float*)d_in[2];
  const float* proj_w = (const float*)d_in[3];
  const float* proj_b = (const float*)d_in[4];
  const float* conv_w = (const float*)d_in[5];
  const float* conv_b = (const float*)d_in[6];
  float* out = (float*)d_out;
  char* ws = (char*)d_ws;

  // Split-K for G: 8 slices (2 blocks/CU) if the workspace can hold the
  // 33.5 MB partial buffer with the weight block relocated past it;
  // otherwise fall back to the verified 4-slice layout (r14, 214.9us).
  const bool big = ws_size >= 104530944UL;
  const int KS = big ? 8 : 4;
  const size_t woff = big ? 102760448UL : 85983232UL;

  u16* xbf = (u16*)(ws);                    // 32 MB
  u16* xT = (u16*)(ws + 33554432);          // 32 MB
  u16* T1bf = (u16*)(ws + 67108864);        // 2 MB (G never materialized)
  float* Gpart = (float*)(ws + 69206016);   // KS*4MB, dead after reduceG_T1
  float* Sf = (float*)(ws + 71303168);      // union w/ Gpart (written after)
  u16* attnT = (u16*)(ws + 75497472);       // union w/ Gpart (written after)
  u16* Mbf = (u16*)(ws + 77594624);         // union w/ Gpart (written after)
  u16* W2bf = (u16*)(ws + 79691776);        // union w/ Gpart (written after)
  // weight block: written by prep_w BEFORE Gpart -> must not overlap Gpart
  u16* WqT = (u16*)(ws + woff);
  u16* Wk = (u16*)(ws + woff + 131072);
  u16* WvT = (u16*)(ws + woff + 262144);
  u16* Pw = (u16*)(ws + woff + 393216);
  u16* cw = (u16*)(ws + woff + 524288);
  float* rws = (float*)(ws + woff + 1703936);
  float* uws = (float*)(ws + woff + 1720320);
  float* wws = (float*)(ws + woff + 1736704);
  float* cb = (float*)(ws + woff + 1753088);
  u16* zbuf = (u16*)(ws + woff + 1769472);

  prep_w_kernel<<<3328, 256, 0, stream>>>(qkv_w, proj_w, conv_w, WqT, Wk, WvT,
                                          Pw, cw, rws, zbuf);
  prep_x_kernel<<<dim3(128, 8, BATCH), 256, 0, stream>>>(x, xbf, xT, rws);

  // G = X*X^T per batch, split-K x KS -> f32 partials
  gemm_glds_kernel<0><<<dim3(4, KS, BATCH), 256, 0, stream>>>(
      xbf, xbf, Gpart, 4096 / KS, 4096, 4096, 256, 2, CN, CN, 65536,
      0.f, nullptr, nullptr, nullptr, nullptr, 0);
  // reduce split-K partials -> T1 directly (G symmetric) + bias_uw
  reduceG_T1_bias_kernel<<<dim3(65, BATCH), 256, 0, stream>>>(
      Gpart, WqT, T1bf, qkv_w, rws, uws, wws, KS);

  // S = (T1 * Wk^T + bias terms) * scale
  gemm_glds_kernel<2><<<dim3(4, 1, BATCH), 256, 0, stream>>>(
      T1bf, Wk, Sf, 256, 256, 256, 256, 2, 65536, 0, 65536,
      0.0625f, qkv_b, qkv_b + 256, uws, wws, 256);

  softmax_kernel<<<BATCH * C, 256, 0, stream>>>(Sf, attnT);

  // M = Pw * attn   (B operand = attn^T)
  gemm_glds_kernel<1><<<dim3(4, 1, BATCH), 256, 0, stream>>>(
      Pw, attnT, Mbf, 256, 256, 256, 256, 2, 0, 65536, 65536,
      0.f, nullptr, nullptr, nullptr, nullptr, 0);
  // W2 = M * Wv (B operand = WvT); 5th block per batch computes cbias
  gemm_glds_kernel<4><<<dim3(5, 1, BATCH), 256, 0, stream>>>(
      Mbf, WvT, W2bf, 256, 256, 256, 256, 2, 65536, 0, 65536,
      0.f, qkv_b, proj_b, nullptr, cb, 256);

  // fused conv + attention-output, single store of out
  convattn_kernel<<<dim3(64, BATCH), 256, 0, stream>>>(xT, cw, W2bf, zbuf,
                                                       conv_b, cb, out);
}

// Round 16
// 213.588 us; speedup vs baseline: 1.0079x; 1.0079x over previous
//
#include <hip/hip_runtime.h>
#include <hip/hip_bf16.h>

typedef unsigned short u16;
typedef __bf16 bf16x8 __attribute__((ext_vector_type(8)));
typedef float f32x4 __attribute__((ext_vector_type(4)));

#define BATCH 16
#define C 256
#define NTOK 4096      // H*W
#define CN 1048576     // C*NTOK

__device__ __forceinline__ u16 f2b(float f) {
  __hip_bfloat16 h = __float2bfloat16(f);
  return __builtin_bit_cast(u16, h);
}
__device__ __forceinline__ float b2f(u16 u) {
  unsigned int x = ((unsigned int)u) << 16;
  return __builtin_bit_cast(float, x);
}

// async global->LDS, 16B per lane. LDS dest must be wave-uniform base
// (HW adds lane*16); global src is per-lane.
__device__ __forceinline__ void glds16(const u16* g, u16* l) {
  __builtin_amdgcn_global_load_lds(
      (const __attribute__((address_space(1))) unsigned int*)(g),
      (__attribute__((address_space(3))) unsigned int*)(l), 16, 0, 0);
}

// ---------------------------------------------------------------------------
// prep_x: x f32 [B][C][N] -> xbf [B][C][N], xT [B][N][C]; row partial sums
// atomically into rws (rws zeroed by prep_w, launched before).
__global__ __launch_bounds__(256) void prep_x_kernel(
    const float* __restrict__ x, u16* __restrict__ xbf, u16* __restrict__ xT,
    float* __restrict__ rws) {
  __shared__ float t[32][33];
  int b = blockIdx.z;
  int c0 = blockIdx.y * 32, n0 = blockIdx.x * 32;
  int tid = threadIdx.x;
  int i = tid >> 3, j4 = (tid & 7) * 4;
  const float* xb = x + (long)b * CN;
  float4 v = *(const float4*)(xb + (long)(c0 + i) * NTOK + n0 + j4);
  ushort4 bv;
  bv.x = f2b(v.x); bv.y = f2b(v.y); bv.z = f2b(v.z); bv.w = f2b(v.w);
  *(ushort4*)(xbf + (long)b * CN + (long)(c0 + i) * NTOK + n0 + j4) = bv;
  t[i][j4 + 0] = v.x; t[i][j4 + 1] = v.y; t[i][j4 + 2] = v.z; t[i][j4 + 3] = v.w;
  __syncthreads();
  ushort4 o;
  o.x = f2b(t[j4 + 0][i]); o.y = f2b(t[j4 + 1][i]);
  o.z = f2b(t[j4 + 2][i]); o.w = f2b(t[j4 + 3][i]);
  *(ushort4*)(xT + (long)b * CN + (long)(n0 + i) * C + c0 + j4) = o;
  if (tid < 32) {
    float s = 0.f;
#pragma unroll
    for (int j = 0; j < 32; ++j) s += t[tid][j];
    atomicAdd(&rws[b * C + c0 + tid], s);
  }
}

// ---------------------------------------------------------------------------
// prep_w: WqT (transposed Wq, for reduceG_T1 matvec), Wk, WvT, Pw, cw.
__global__ __launch_bounds__(256) void prep_w_kernel(
    const float* __restrict__ qkv_w, const float* __restrict__ proj_w,
    const float* __restrict__ conv_w, u16* __restrict__ WqT, u16* __restrict__ Wk,
    u16* __restrict__ WvT, u16* __restrict__ Pw, u16* __restrict__ cw,
    float* __restrict__ rws, u16* __restrict__ zbuf) {
  int idx = blockIdx.x * 256 + threadIdx.x;
  if (idx < 4096) rws[idx] = 0.f;
  if (idx < 256) zbuf[idx] = 0;
  if (idx < 65536) {
    // WqT[k][r] = Wq[r][k]; coalesced read, scattered write
    WqT[(idx & 255) * 256 + (idx >> 8)] = f2b(qkv_w[idx]);
  } else if (idx < 131072) {
    int e = idx - 65536;
    Wk[e] = f2b(qkv_w[65536 + e]);
  } else if (idx < 196608) {
    int e = idx - 131072;
    int i = e >> 8, d = e & 255;
    WvT[e] = f2b(qkv_w[131072 + d * 256 + i]);
  } else if (idx < 262144) {
    int e = idx - 196608;
    Pw[e] = f2b(proj_w[e]);
  } else if (idx < 851968) {
    int e = idx - 262144;
    int o = e / 2304;
    int rem = e - o * 2304;
    int tap = rem >> 8, i = rem & 255;
    cw[e] = f2b(conv_w[o * 2304 + i * 9 + tap]);
  }
}

// ---------------------------------------------------------------------------
// Generic GEMM C = A*B^T (both K-contiguous), 128x128 tile, BK=32, 4 waves,
// global_load_lds staging + slot-XOR swizzle, double-buffered.
// EPI 1: bf16. EPI 2: S-epi. EPI 4: bf16 + extra cbias block at x==4.
// EPI 5: bf16 partial store at ((b*gridDim.y)+ks)*sC (split-K slices).
template <int EPI>
__global__ __launch_bounds__(256, 2) void gemm_glds_kernel(
    const u16* __restrict__ A, const u16* __restrict__ B, void* __restrict__ Cv,
    int K, int lda, int ldb, int ldc, int tilesN, long sA, long sB, long sC,
    float scale, const float* __restrict__ e1, const float* __restrict__ e2,
    const float* __restrict__ e3, const float* __restrict__ e4, int e34stride) {
  if (EPI == 4 && blockIdx.x == 4) {
    // cbias: cb[b][j] = proj_b[j] + sum_d M[b][j][d]*qkv_b[512+d]
    int bb = blockIdx.z, j = threadIdx.x;
    const u16* m = A + (long)bb * sA + (long)j * 256;
    float s = 0.f;
    for (int d = 0; d < 256; ++d) s += b2f(m[d]) * e1[512 + d];
    float* cbout = const_cast<float*>(e4);
    cbout[bb * 256 + j] = e2[j] + s;
    return;
  }
  int b = blockIdx.z, ks = blockIdx.y;
  A += (long)b * sA + (long)ks * K;
  B += (long)b * sB + (long)ks * K;
  int ty = blockIdx.x / tilesN, tx = blockIdx.x % tilesN;
  int row0 = ty * 128, col0 = tx * 128;

  __shared__ u16 lA[2][4096];
  __shared__ u16 lB[2][4096];

  int tid = threadIdx.x;
  int lane = tid & 63, wv = tid >> 6;
  int wm = wv >> 1, wn = wv & 1;
  int fr = lane & 15, kq = lane >> 4;
  int kqs = kq ^ ((fr >> 1) & 3);

  int c0 = wv * 128 + lane, c1 = c0 + 64;
  int r0s = c0 >> 2, r1s = c1 >> 2;
  int ls0 = (c0 & 3) ^ ((r0s >> 1) & 3);
  int ls1 = (c1 & 3) ^ ((r1s >> 1) & 3);
  const u16* pA0 = A + (long)(row0 + r0s) * lda + ls0 * 8;
  const u16* pA1 = A + (long)(row0 + r1s) * lda + ls1 * 8;
  const u16* pB0 = B + (long)(col0 + r0s) * ldb + ls0 * 8;
  const u16* pB1 = B + (long)(col0 + r1s) * ldb + ls1 * 8;
  int dst0 = wv * 1024, dst1 = wv * 1024 + 512;

  f32x4 acc[4][4] = {};

  auto STAGE = [&](int buf, int t) {
    int k0 = t << 5;
    glds16(pA0 + k0, &lA[buf][dst0]);
    glds16(pA1 + k0, &lA[buf][dst1]);
    glds16(pB0 + k0, &lB[buf][dst0]);
    glds16(pB1 + k0, &lB[buf][dst1]);
  };
  auto COMPUTE = [&](int buf) {
    bf16x8 af[4], bfr[4];
#pragma unroll
    for (int m = 0; m < 4; ++m)
      af[m] = *(const bf16x8*)&lA[buf][(wm * 64 + m * 16 + fr) * 32 + kqs * 8];
#pragma unroll
    for (int n = 0; n < 4; ++n)
      bfr[n] = *(const bf16x8*)&lB[buf][(wn * 64 + n * 16 + fr) * 32 + kqs * 8];
#pragma unroll
    for (int m = 0; m < 4; ++m)
#pragma unroll
      for (int n = 0; n < 4; ++n)
        acc[m][n] = __builtin_amdgcn_mfma_f32_16x16x32_bf16(af[m], bfr[n], acc[m][n], 0, 0, 0);
  };

  int nk = K >> 5, cur = 0;
  STAGE(0, 0);
  __syncthreads();
  for (int t = 0; t < nk; ++t) {
    if (t + 1 < nk) STAGE(cur ^ 1, t + 1);
    COMPUTE(cur);
    __syncthreads();
    cur ^= 1;
  }

  if (EPI == 5) {
    __hip_bfloat16* Cb =
        (__hip_bfloat16*)Cv + ((long)b * gridDim.y + ks) * sC;
#pragma unroll
    for (int m = 0; m < 4; ++m)
#pragma unroll
      for (int n = 0; n < 4; ++n)
#pragma unroll
        for (int r = 0; r < 4; ++r) {
          int gr = row0 + wm * 64 + m * 16 + kq * 4 + r;
          int gc = col0 + wn * 64 + n * 16 + fr;
          Cb[(long)gr * ldc + gc] = __float2bfloat16(acc[m][n][r]);
        }
  } else if (EPI == 1 || EPI == 4) {
    __hip_bfloat16* Cb = (__hip_bfloat16*)Cv + (long)b * sC;
#pragma unroll
    for (int m = 0; m < 4; ++m)
#pragma unroll
      for (int n = 0; n < 4; ++n)
#pragma unroll
        for (int r = 0; r < 4; ++r) {
          int gr = row0 + wm * 64 + m * 16 + kq * 4 + r;
          int gc = col0 + wn * 64 + n * 16 + fr;
          Cb[(long)gr * ldc + gc] = __float2bfloat16(acc[m][n][r]);
        }
  } else if (EPI == 2) {
    float* Cb = (float*)Cv + (long)b * sC;
    const float* ub = e3 + (long)b * e34stride;
    const float* wb = e4 + (long)b * e34stride;
#pragma unroll
    for (int m = 0; m < 4; ++m)
#pragma unroll
      for (int n = 0; n < 4; ++n)
#pragma unroll
        for (int r = 0; r < 4; ++r) {
          int gr = row0 + wm * 64 + m * 16 + kq * 4 + r;
          int gc = col0 + wn * 64 + n * 16 + fr;
          float v = acc[m][n][r] + e1[gr] * ub[gc] + e2[gc] * wb[gr] +
                    4096.0f * e1[gr] * e2[gc];
          Cb[(long)gr * ldc + gc] = v * scale;
        }
  }
}

// ---------------------------------------------------------------------------
// reduceG + T1 + bias_uw merged. grid (65, B). Partials are bf16 (8 slices).
// x<64: sum 8 bf16 split-K partials of G rows [4x..4x+4) (f32 accum);
//       G symmetric -> T1[c][d] = sum_i Wq[c,i]*G[d,i]; thread c computes
//       the 4 T1 columns d=4x..4x+3 via WqT (coalesced) x LDS g (broadcast).
// x==64: u[b][t]=Wk[t,:]*r[b,:], w[b][t]=Wq[t,:]*r[b,:].
__global__ __launch_bounds__(256) void reduceG_T1_bias_kernel(
    const u16* __restrict__ Gp, const u16* __restrict__ WqT,
    u16* __restrict__ T1, const float* __restrict__ qkv_w,
    const float* __restrict__ r, float* __restrict__ u, float* __restrict__ w) {
  int b = blockIdx.y;
  if (blockIdx.x < 64) {
    __shared__ float g[4][256];
    int tid = threadIdx.x;
    int e = blockIdx.x * 1024 + tid * 4;
    const u16* base = Gp + (long)b * 8 * 65536;
    float s0 = 0.f, s1 = 0.f, s2 = 0.f, s3 = 0.f;
#pragma unroll
    for (int sl = 0; sl < 8; ++sl) {
      ushort4 v = *(const ushort4*)(base + (long)sl * 65536 + e);
      s0 += b2f(v.x); s1 += b2f(v.y); s2 += b2f(v.z); s3 += b2f(v.w);
    }
    int rr = tid >> 6, cc = (tid & 63) * 4;
    g[rr][cc + 0] = s0; g[rr][cc + 1] = s1;
    g[rr][cc + 2] = s2; g[rr][cc + 3] = s3;
    __syncthreads();
    int c = tid;
    float a0 = 0.f, a1 = 0.f, a2 = 0.f, a3 = 0.f;
#pragma unroll 4
    for (int i = 0; i < 256; ++i) {
      float wq = b2f(WqT[i * 256 + c]);
      a0 += wq * g[0][i]; a1 += wq * g[1][i];
      a2 += wq * g[2][i]; a3 += wq * g[3][i];
    }
    ushort4 o;
    o.x = f2b(a0); o.y = f2b(a1); o.z = f2b(a2); o.w = f2b(a3);
    *(ushort4*)(T1 + (long)b * 65536 + (long)c * 256 + blockIdx.x * 4) = o;
  } else {
    int t = threadIdx.x;
    const float* rb = r + b * C;
    float su = 0.f, sw = 0.f;
    for (int i = 0; i < C; ++i) {
      float rv = rb[i];
      su += qkv_w[(256 + t) * 256 + i] * rv;
      sw += qkv_w[t * 256 + i] * rv;
    }
    u[b * C + t] = su;
    w[b * C + t] = sw;
  }
}

// ---------------------------------------------------------------------------
// softmax over rows of S -> attn^T bf16 (attnT[d][c] = attn[c][d])
__global__ __launch_bounds__(256) void softmax_kernel(const float* __restrict__ S,
                                                      u16* __restrict__ attnT) {
  int row = blockIdx.x;
  int t = threadIdx.x;
  float v = S[(long)row * C + t];
  __shared__ float red[256];
  red[t] = v; __syncthreads();
  for (int st = 128; st > 0; st >>= 1) {
    if (t < st) red[t] = fmaxf(red[t], red[t + st]);
    __syncthreads();
  }
  float mx = red[0];
  __syncthreads();
  float e = __expf(v - mx);
  red[t] = e; __syncthreads();
  for (int st = 128; st > 0; st >>= 1) {
    if (t < st) red[t] += red[t + st];
    __syncthreads();
  }
  float inv = 1.0f / red[0];
  int b = row >> 8, c = row & 255;
  attnT[(long)b * 65536 + t * 256 + c] = f2b(e * inv);
}

// ---------------------------------------------------------------------------
// Fused conv3x3 implicit-GEMM + attention-output GEMM, BK=64 (proven:
// 104us, MfmaUtil 36%, 0 bank conflicts). 128x128 tile, 4 waves, acc[4][4];
// merged conv+attn accumulator. 10 taps (9 conv + 1 attn) x 4 chunks of 64-K
// = 40 barrier-steps. 2 LDS buffers [128][64] (64KB -> 2 blocks/CU).
// Slot swizzle: LDS[row][slot] holds global slot (slot ^ (row&7)); read
// applies same XOR. Structure notes: per-wave tiles >64x64 spill (r3/r13);
// A-from-global gathers serialize VMEM (r9); BK=32 doesn't raise occupancy
// (r12). This config is the measured optimum of the explored space.
__global__ __launch_bounds__(256, 2) void convattn_kernel(
    const u16* __restrict__ xT, const u16* __restrict__ cw,
    const u16* __restrict__ W2, const u16* __restrict__ zbuf,
    const float* __restrict__ conv_b, const float* __restrict__ cb,
    float* __restrict__ out) {
  int b = blockIdx.y;
  int to = blockIdx.x >> 5;  // 0..1
  int tn = blockIdx.x & 31;  // 0..31
  int row0 = to * 128, col0 = tn * 128;
  const u16* xTb = xT + (long)b * CN;
  const u16* W2b = W2 + (long)b * 65536;

  __shared__ u16 lA[2][8192];   // [128][64] u16 per buffer
  __shared__ u16 lB[2][8192];

  int tid = threadIdx.x;
  int lane = tid & 63, w = tid >> 6;
  int wm = w >> 1, wn = w & 1;
  int fr = lane & 15, kq = lane >> 4;
  int fx = fr & 7;              // == row&7 for all fragment rows

  // staging decomp: each wave stages rows [w*32, w*32+32), 4 instrs of 8 rows
  int lr = lane >> 3, sl = lane & 7;
  int ss = sl ^ lr;             // swizzled source slot (row&7 == lr)

  const u16* aA[4]; const u16* pBt[4]; int hh[4], ww[4];
  const u16* zsrc = zbuf + ss * 8;
#pragma unroll
  for (int i = 0; i < 4; ++i) {
    int r = w * 32 + i * 8 + lr;
    aA[i] = cw + (long)(row0 + r) * 2304 + ss * 8;
    int t = col0 + r;
    hh[i] = t >> 6; ww[i] = t & 63;
    pBt[i] = xTb + (long)t * 256 + ss * 8;
  }
  int nb = col0 >> 8, jb = col0 & 255;

  f32x4 acc[4][4] = {};
  const u16 *at0, *at1, *at2, *at3, *bt0, *bt1, *bt2, *bt3;

  auto set_tap = [&](int tap) {
    int dh = tap / 3 - 1, dw = tap % 3 - 1;
    long sh = (long)(dh * 64 + dw) * 256;
    at0 = aA[0] + tap * 256; at1 = aA[1] + tap * 256;
    at2 = aA[2] + tap * 256; at3 = aA[3] + tap * 256;
    bool v0 = ((unsigned)(hh[0] + dh) < 64u) && ((unsigned)(ww[0] + dw) < 64u);
    bool v1 = ((unsigned)(hh[1] + dh) < 64u) && ((unsigned)(ww[1] + dw) < 64u);
    bool v2 = ((unsigned)(hh[2] + dh) < 64u) && ((unsigned)(ww[2] + dw) < 64u);
    bool v3 = ((unsigned)(hh[3] + dh) < 64u) && ((unsigned)(ww[3] + dw) < 64u);
    bt0 = v0 ? pBt[0] + sh : zsrc;
    bt1 = v1 ? pBt[1] + sh : zsrc;
    bt2 = v2 ? pBt[2] + sh : zsrc;
    bt3 = v3 ? pBt[3] + sh : zsrc;
  };
  auto set_attn = [&]() {
#pragma unroll
    for (int i = 0; i < 4; ++i) {
      int r = w * 32 + i * 8 + lr;
      const u16* a = xTb + (long)((row0 + r) * 16 + nb) * 256 + ss * 8;
      const u16* bb = W2b + (long)(jb + r) * 256 + ss * 8;
      if (i == 0) { at0 = a; bt0 = bb; }
      else if (i == 1) { at1 = a; bt1 = bb; }
      else if (i == 2) { at2 = a; bt2 = bb; }
      else { at3 = a; bt3 = bb; }
    }
  };

  auto STAGE = [&](int buf, int chunk) {
    int k = chunk * 64;
    glds16(at0 + k, &lA[buf][(w * 32 + 0) * 64]);
    glds16(at1 + k, &lA[buf][(w * 32 + 8) * 64]);
    glds16(at2 + k, &lA[buf][(w * 32 + 16) * 64]);
    glds16(at3 + k, &lA[buf][(w * 32 + 24) * 64]);
    glds16(bt0 + k, &lB[buf][(w * 32 + 0) * 64]);
    glds16(bt1 + k, &lB[buf][(w * 32 + 8) * 64]);
    glds16(bt2 + k, &lB[buf][(w * 32 + 16) * 64]);
    glds16(bt3 + k, &lB[buf][(w * 32 + 24) * 64]);
  };
  auto COMPUTE = [&](int buf) {
    bf16x8 af[4][2], bf[4][2];
#pragma unroll
    for (int m = 0; m < 4; ++m) {
      int row = wm * 64 + m * 16 + fr;
#pragma unroll
      for (int kh = 0; kh < 2; ++kh)
        af[m][kh] = *(const bf16x8*)&lA[buf][row * 64 + (((kh << 2) + kq) ^ fx) * 8];
    }
#pragma unroll
    for (int n = 0; n < 4; ++n) {
      int row = wn * 64 + n * 16 + fr;
#pragma unroll
      for (int kh = 0; kh < 2; ++kh)
        bf[n][kh] = *(const bf16x8*)&lB[buf][row * 64 + (((kh << 2) + kq) ^ fx) * 8];
    }
    __builtin_amdgcn_s_setprio(1);
#pragma unroll
    for (int kh = 0; kh < 2; ++kh)
#pragma unroll
      for (int m = 0; m < 4; ++m)
#pragma unroll
        for (int n = 0; n < 4; ++n)
          acc[m][n] = __builtin_amdgcn_mfma_f32_16x16x32_bf16(af[m][kh], bf[n][kh], acc[m][n], 0, 0, 0);
    __builtin_amdgcn_s_setprio(0);
  };

  set_tap(0);
  STAGE(0, 0);
  asm volatile("s_waitcnt vmcnt(0)" ::: "memory");
  __builtin_amdgcn_sched_barrier(0);
  __builtin_amdgcn_s_barrier();
  __builtin_amdgcn_sched_barrier(0);

  int buf = 0;
#pragma unroll 1
  for (int T = 0; T < 10; ++T) {
#pragma unroll
    for (int j = 0; j < 4; ++j) {
      if (!(T == 9 && j == 3)) {
        if (j < 3) {
          STAGE(buf ^ 1, j + 1);
        } else {
          if (T < 8) set_tap(T + 1);
          else set_attn();
          STAGE(buf ^ 1, 0);
        }
      }
      COMPUTE(buf);
      asm volatile("s_waitcnt vmcnt(0)" ::: "memory");
      __builtin_amdgcn_sched_barrier(0);
      __builtin_amdgcn_s_barrier();
      __builtin_amdgcn_sched_barrier(0);
      buf ^= 1;
    }
  }

  float* ob = out + (long)b * CN;
  const float* cbb = cb + b * C;
#pragma unroll
  for (int m = 0; m < 4; ++m) {
    int go = row0 + wm * 64 + m * 16 + kq * 4;
#pragma unroll
    for (int nn = 0; nn < 4; ++nn) {
      int cc = wn * 64 + nn * 16 + fr;
      float cbv = cbb[jb + cc];
#pragma unroll
      for (int r = 0; r < 4; ++r)
        ob[(long)(go + r) * NTOK + col0 + cc] =
            acc[m][nn][r] + conv_b[go + r] + cbv;
    }
  }
}

// ---------------------------------------------------------------------------
extern "C" void kernel_launch(void* const* d_in, const int* in_sizes, int n_in,
                              void* d_out, int out_size, void* d_ws, size_t ws_size,
                              hipStream_t stream) {
  const float* x = (const float*)d_in[0];
  const float* qkv_w = (const float*)d_in[1];
  const float* qkv_b = (const float*)d_in[2];
  const float* proj_w = (const float*)d_in[3];
  const float* proj_b = (const float*)d_in[4];
  const float* conv_w = (const float*)d_in[5];
  const float* conv_b = (const float*)d_in[6];
  float* out = (float*)d_out;
  char* ws = (char*)d_ws;

  u16* xbf = (u16*)(ws);                    // 32 MB
  u16* xT = (u16*)(ws + 33554432);          // 32 MB
  u16* T1bf = (u16*)(ws + 67108864);        // 2 MB (G never materialized)
  u16* Gpart = (u16*)(ws + 69206016);       // 8 bf16 slices x 16 b = 16 MB,
                                            // dead after reduceG_T1
  float* Sf = (float*)(ws + 71303168);      // union w/ Gpart (written after)
  u16* attnT = (u16*)(ws + 75497472);       // union w/ Gpart (written after)
  u16* Mbf = (u16*)(ws + 77594624);         // union w/ Gpart (written after)
  u16* W2bf = (u16*)(ws + 79691776);        // union w/ Gpart (written after)
  u16* WqT = (u16*)(ws + 85983232);
  u16* Wk = (u16*)(ws + 86114304);
  u16* WvT = (u16*)(ws + 86245376);
  u16* Pw = (u16*)(ws + 86376448);
  u16* cw = (u16*)(ws + 86507520);
  float* rws = (float*)(ws + 87687168);
  float* uws = (float*)(ws + 87703552);
  float* wws = (float*)(ws + 87719936);
  float* cb = (float*)(ws + 87736320);
  u16* zbuf = (u16*)(ws + 87752704);

  prep_w_kernel<<<3328, 256, 0, stream>>>(qkv_w, proj_w, conv_w, WqT, Wk, WvT,
                                          Pw, cw, rws, zbuf);
  prep_x_kernel<<<dim3(128, 8, BATCH), 256, 0, stream>>>(x, xbf, xT, rws);

  // G = X*X^T per batch, split-K x8 -> bf16 partials (2 blocks/CU)
  gemm_glds_kernel<5><<<dim3(4, 8, BATCH), 256, 0, stream>>>(
      xbf, xbf, Gpart, 512, 4096, 4096, 256, 2, CN, CN, 65536,
      0.f, nullptr, nullptr, nullptr, nullptr, 0);
  // reduce bf16 split-K partials -> T1 directly (G symmetric) + bias_uw
  reduceG_T1_bias_kernel<<<dim3(65, BATCH), 256, 0, stream>>>(
      Gpart, WqT, T1bf, qkv_w, rws, uws, wws);

  // S = (T1 * Wk^T + bias terms) * scale
  gemm_glds_kernel<2><<<dim3(4, 1, BATCH), 256, 0, stream>>>(
      T1bf, Wk, Sf, 256, 256, 256, 256, 2, 65536, 0, 65536,
      0.0625f, qkv_b, qkv_b + 256, uws, wws, 256);

  softmax_kernel<<<BATCH * C, 256, 0, stream>>>(Sf, attnT);

  // M = Pw * attn   (B operand = attn^T)
  gemm_glds_kernel<1><<<dim3(4, 1, BATCH), 256, 0, stream>>>(
      Pw, attnT, Mbf, 256, 256, 256, 256, 2, 0, 65536, 65536,
      0.f, nullptr, nullptr, nullptr, nullptr, 0);
  // W2 = M * Wv (B operand = WvT); 5th block per batch computes cbias
  gemm_glds_kernel<4><<<dim3(5, 1, BATCH), 256, 0, stream>>>(
      Mbf, WvT, W2bf, 256, 256, 256, 256, 2, 65536, 0, 65536,
      0.f, qkv_b, proj_b, nullptr, cb, 256);

  // fused conv + attention-output, single store of out
  convattn_kernel<<<dim3(64, BATCH), 256, 0, stream>>>(xT, cw, W2bf, zbuf,
                                                       conv_b, cb, out);
}

// Round 17
// 206.963 us; speedup vs baseline: 1.0402x; 1.0320x over previous
//
#include <hip/hip_runtime.h>
#include <hip/hip_bf16.h>

typedef unsigned short u16;
typedef __bf16 bf16x8 __attribute__((ext_vector_type(8)));
typedef float f32x4 __attribute__((ext_vector_type(4)));

#define BATCH 16
#define C 256
#define NTOK 4096      // H*W
#define CN 1048576     // C*NTOK

__device__ __forceinline__ u16 f2b(float f) {
  __hip_bfloat16 h = __float2bfloat16(f);
  return __builtin_bit_cast(u16, h);
}
__device__ __forceinline__ float b2f(u16 u) {
  unsigned int x = ((unsigned int)u) << 16;
  return __builtin_bit_cast(float, x);
}

// async global->LDS, 16B per lane. LDS dest must be wave-uniform base
// (HW adds lane*16); global src is per-lane.
__device__ __forceinline__ void glds16(const u16* g, u16* l) {
  __builtin_amdgcn_global_load_lds(
      (const __attribute__((address_space(1))) unsigned int*)(g),
      (__attribute__((address_space(3))) unsigned int*)(l), 16, 0, 0);
}

// ---------------------------------------------------------------------------
// prep_x: x f32 [B][C][N] -> xbf [B][C][N], xT [B][N][C]; row partial sums
// atomically into rws (rws zeroed by prep_w, launched before).
__global__ __launch_bounds__(256) void prep_x_kernel(
    const float* __restrict__ x, u16* __restrict__ xbf, u16* __restrict__ xT,
    float* __restrict__ rws) {
  __shared__ float t[32][33];
  int b = blockIdx.z;
  int c0 = blockIdx.y * 32, n0 = blockIdx.x * 32;
  int tid = threadIdx.x;
  int i = tid >> 3, j4 = (tid & 7) * 4;
  const float* xb = x + (long)b * CN;
  float4 v = *(const float4*)(xb + (long)(c0 + i) * NTOK + n0 + j4);
  ushort4 bv;
  bv.x = f2b(v.x); bv.y = f2b(v.y); bv.z = f2b(v.z); bv.w = f2b(v.w);
  *(ushort4*)(xbf + (long)b * CN + (long)(c0 + i) * NTOK + n0 + j4) = bv;
  t[i][j4 + 0] = v.x; t[i][j4 + 1] = v.y; t[i][j4 + 2] = v.z; t[i][j4 + 3] = v.w;
  __syncthreads();
  ushort4 o;
  o.x = f2b(t[j4 + 0][i]); o.y = f2b(t[j4 + 1][i]);
  o.z = f2b(t[j4 + 2][i]); o.w = f2b(t[j4 + 3][i]);
  *(ushort4*)(xT + (long)b * CN + (long)(n0 + i) * C + c0 + j4) = o;
  if (tid < 32) {
    float s = 0.f;
#pragma unroll
    for (int j = 0; j < 32; ++j) s += t[tid][j];
    atomicAdd(&rws[b * C + c0 + tid], s);
  }
}

// ---------------------------------------------------------------------------
// prep_w: WqT (transposed Wq, for reduceG_T1 matvec), Wk, WvT, Pw, cw.
__global__ __launch_bounds__(256) void prep_w_kernel(
    const float* __restrict__ qkv_w, const float* __restrict__ proj_w,
    const float* __restrict__ conv_w, u16* __restrict__ WqT, u16* __restrict__ Wk,
    u16* __restrict__ WvT, u16* __restrict__ Pw, u16* __restrict__ cw,
    float* __restrict__ rws, u16* __restrict__ zbuf) {
  int idx = blockIdx.x * 256 + threadIdx.x;
  if (idx < 4096) rws[idx] = 0.f;
  if (idx < 256) zbuf[idx] = 0;
  if (idx < 65536) {
    // WqT[k][r] = Wq[r][k]; coalesced read, scattered write
    WqT[(idx & 255) * 256 + (idx >> 8)] = f2b(qkv_w[idx]);
  } else if (idx < 131072) {
    int e = idx - 65536;
    Wk[e] = f2b(qkv_w[65536 + e]);
  } else if (idx < 196608) {
    int e = idx - 131072;
    int i = e >> 8, d = e & 255;
    WvT[e] = f2b(qkv_w[131072 + d * 256 + i]);
  } else if (idx < 262144) {
    int e = idx - 196608;
    Pw[e] = f2b(proj_w[e]);
  } else if (idx < 851968) {
    int e = idx - 262144;
    int o = e / 2304;
    int rem = e - o * 2304;
    int tap = rem >> 8, i = rem & 255;
    cw[e] = f2b(conv_w[o * 2304 + i * 9 + tap]);
  }
}

// ---------------------------------------------------------------------------
// Generic GEMM C = A*B^T, 128x128 tile, BK=32, 4 waves, glds+swizzle.
// EPI 5: bf16 partial store at ((b*gridDim.y)+ks)*sC (split-K slices).
template <int EPI>
__global__ __launch_bounds__(256, 2) void gemm_glds_kernel(
    const u16* __restrict__ A, const u16* __restrict__ B, void* __restrict__ Cv,
    int K, int lda, int ldb, int ldc, int tilesN, long sA, long sB, long sC,
    float scale, const float* __restrict__ e1, const float* __restrict__ e2,
    const float* __restrict__ e3, const float* __restrict__ e4, int e34stride) {
  int b = blockIdx.z, ks = blockIdx.y;
  A += (long)b * sA + (long)ks * K;
  B += (long)b * sB + (long)ks * K;
  int ty = blockIdx.x / tilesN, tx = blockIdx.x % tilesN;
  int row0 = ty * 128, col0 = tx * 128;

  __shared__ u16 lA[2][4096];
  __shared__ u16 lB[2][4096];

  int tid = threadIdx.x;
  int lane = tid & 63, wv = tid >> 6;
  int wm = wv >> 1, wn = wv & 1;
  int fr = lane & 15, kq = lane >> 4;
  int kqs = kq ^ ((fr >> 1) & 3);

  int c0 = wv * 128 + lane, c1 = c0 + 64;
  int r0s = c0 >> 2, r1s = c1 >> 2;
  int ls0 = (c0 & 3) ^ ((r0s >> 1) & 3);
  int ls1 = (c1 & 3) ^ ((r1s >> 1) & 3);
  const u16* pA0 = A + (long)(row0 + r0s) * lda + ls0 * 8;
  const u16* pA1 = A + (long)(row0 + r1s) * lda + ls1 * 8;
  const u16* pB0 = B + (long)(col0 + r0s) * ldb + ls0 * 8;
  const u16* pB1 = B + (long)(col0 + r1s) * ldb + ls1 * 8;
  int dst0 = wv * 1024, dst1 = wv * 1024 + 512;

  f32x4 acc[4][4] = {};

  auto STAGE = [&](int buf, int t) {
    int k0 = t << 5;
    glds16(pA0 + k0, &lA[buf][dst0]);
    glds16(pA1 + k0, &lA[buf][dst1]);
    glds16(pB0 + k0, &lB[buf][dst0]);
    glds16(pB1 + k0, &lB[buf][dst1]);
  };
  auto COMPUTE = [&](int buf) {
    bf16x8 af[4], bfr[4];
#pragma unroll
    for (int m = 0; m < 4; ++m)
      af[m] = *(const bf16x8*)&lA[buf][(wm * 64 + m * 16 + fr) * 32 + kqs * 8];
#pragma unroll
    for (int n = 0; n < 4; ++n)
      bfr[n] = *(const bf16x8*)&lB[buf][(wn * 64 + n * 16 + fr) * 32 + kqs * 8];
#pragma unroll
    for (int m = 0; m < 4; ++m)
#pragma unroll
      for (int n = 0; n < 4; ++n)
        acc[m][n] = __builtin_amdgcn_mfma_f32_16x16x32_bf16(af[m], bfr[n], acc[m][n], 0, 0, 0);
  };

  int nk = K >> 5, cur = 0;
  STAGE(0, 0);
  __syncthreads();
  for (int t = 0; t < nk; ++t) {
    if (t + 1 < nk) STAGE(cur ^ 1, t + 1);
    COMPUTE(cur);
    __syncthreads();
    cur ^= 1;
  }

  if (EPI == 5) {
    __hip_bfloat16* Cb =
        (__hip_bfloat16*)Cv + ((long)b * gridDim.y + ks) * sC;
#pragma unroll
    for (int m = 0; m < 4; ++m)
#pragma unroll
      for (int n = 0; n < 4; ++n)
#pragma unroll
        for (int r = 0; r < 4; ++r) {
          int gr = row0 + wm * 64 + m * 16 + kq * 4 + r;
          int gc = col0 + wn * 64 + n * 16 + fr;
          Cb[(long)gr * ldc + gc] = __float2bfloat16(acc[m][n][r]);
        }
  }
}

// ---------------------------------------------------------------------------
// Small GEMM C = A*B^T (256x256 per batch), 64x64 tiles, 4 waves, wave=32x32,
// acc[2][2], BK=32, glds+swizzle (same involution as 128 kernel), dbuf.
// Grid (16,1,B) — 256 blocks = 1/CU (vs 64 blocks at 128 tiles).
// EPI 1: bf16. EPI 2: S-epi (f32). EPI 4: bf16 + cbias block at x==16.
template <int EPI>
__global__ __launch_bounds__(256, 2) void gemm64_kernel(
    const u16* __restrict__ A, const u16* __restrict__ B, void* __restrict__ Cv,
    long sA, long sB, long sC, float scale, const float* __restrict__ e1,
    const float* __restrict__ e2, const float* __restrict__ e3,
    const float* __restrict__ e4, int e34stride) {
  if (EPI == 4 && blockIdx.x == 16) {
    // cbias: cb[b][j] = proj_b[j] + sum_d M[b][j][d]*qkv_b[512+d]
    int bb = blockIdx.z, j = threadIdx.x;
    const u16* m = A + (long)bb * sA + (long)j * 256;
    float s = 0.f;
    for (int d = 0; d < 256; ++d) s += b2f(m[d]) * e1[512 + d];
    float* cbout = const_cast<float*>(e4);
    cbout[bb * 256 + j] = e2[j] + s;
    return;
  }
  int b = blockIdx.z;
  A += (long)b * sA;
  B += (long)b * sB;
  int ty = blockIdx.x >> 2, tx = blockIdx.x & 3;
  int row0 = ty * 64, col0 = tx * 64;

  __shared__ u16 lA[2][2048];   // [64][32]
  __shared__ u16 lB[2][2048];

  int tid = threadIdx.x;
  int lane = tid & 63, w = tid >> 6;
  int wm = w >> 1, wn = w & 1;
  int fr = lane & 15, kq = lane >> 4;
  int kqs = kq ^ ((fr >> 1) & 3);

  int rs = tid >> 2;                        // 0..63
  int ls = (tid & 3) ^ ((rs >> 1) & 3);     // swizzled 16B slot
  const u16* pA = A + (long)(row0 + rs) * 256 + ls * 8;
  const u16* pB = B + (long)(col0 + rs) * 256 + ls * 8;
  int dst = w * 512;                        // wave-uniform (16 rows x 32 u16)

  f32x4 acc[2][2] = {};

  auto STAGE = [&](int buf, int t) {
    int k0 = t << 5;
    glds16(pA + k0, &lA[buf][dst]);
    glds16(pB + k0, &lB[buf][dst]);
  };
  auto COMPUTE = [&](int buf) {
    bf16x8 af[2], bfr[2];
#pragma unroll
    for (int m = 0; m < 2; ++m)
      af[m] = *(const bf16x8*)&lA[buf][(wm * 32 + m * 16 + fr) * 32 + kqs * 8];
#pragma unroll
    for (int n = 0; n < 2; ++n)
      bfr[n] = *(const bf16x8*)&lB[buf][(wn * 32 + n * 16 + fr) * 32 + kqs * 8];
#pragma unroll
    for (int m = 0; m < 2; ++m)
#pragma unroll
      for (int n = 0; n < 2; ++n)
        acc[m][n] = __builtin_amdgcn_mfma_f32_16x16x32_bf16(af[m], bfr[n], acc[m][n], 0, 0, 0);
  };

  int cur = 0;
  STAGE(0, 0);
  __syncthreads();
  for (int t = 0; t < 8; ++t) {
    if (t + 1 < 8) STAGE(cur ^ 1, t + 1);
    COMPUTE(cur);
    __syncthreads();
    cur ^= 1;
  }

  if (EPI == 1 || EPI == 4) {
    __hip_bfloat16* Cb = (__hip_bfloat16*)Cv + (long)b * sC;
#pragma unroll
    for (int m = 0; m < 2; ++m)
#pragma unroll
      for (int n = 0; n < 2; ++n)
#pragma unroll
        for (int r = 0; r < 4; ++r) {
          int gr = row0 + wm * 32 + m * 16 + kq * 4 + r;
          int gc = col0 + wn * 32 + n * 16 + fr;
          Cb[(long)gr * 256 + gc] = __float2bfloat16(acc[m][n][r]);
        }
  } else if (EPI == 2) {
    float* Cb = (float*)Cv + (long)b * sC;
    const float* ub = e3 + (long)b * e34stride;
    const float* wb = e4 + (long)b * e34stride;
#pragma unroll
    for (int m = 0; m < 2; ++m)
#pragma unroll
      for (int n = 0; n < 2; ++n)
#pragma unroll
        for (int r = 0; r < 4; ++r) {
          int gr = row0 + wm * 32 + m * 16 + kq * 4 + r;
          int gc = col0 + wn * 32 + n * 16 + fr;
          float v = acc[m][n][r] + e1[gr] * ub[gc] + e2[gc] * wb[gr] +
                    4096.0f * e1[gr] * e2[gc];
          Cb[(long)gr * 256 + gc] = v * scale;
        }
  }
}

// ---------------------------------------------------------------------------
// reduceG + T1 + bias_uw merged. grid (65, B). Partials are bf16 (8 slices).
__global__ __launch_bounds__(256) void reduceG_T1_bias_kernel(
    const u16* __restrict__ Gp, const u16* __restrict__ WqT,
    u16* __restrict__ T1, const float* __restrict__ qkv_w,
    const float* __restrict__ r, float* __restrict__ u, float* __restrict__ w) {
  int b = blockIdx.y;
  if (blockIdx.x < 64) {
    __shared__ float g[4][256];
    int tid = threadIdx.x;
    int e = blockIdx.x * 1024 + tid * 4;
    const u16* base = Gp + (long)b * 8 * 65536;
    float s0 = 0.f, s1 = 0.f, s2 = 0.f, s3 = 0.f;
#pragma unroll
    for (int sl = 0; sl < 8; ++sl) {
      ushort4 v = *(const ushort4*)(base + (long)sl * 65536 + e);
      s0 += b2f(v.x); s1 += b2f(v.y); s2 += b2f(v.z); s3 += b2f(v.w);
    }
    int rr = tid >> 6, cc = (tid & 63) * 4;
    g[rr][cc + 0] = s0; g[rr][cc + 1] = s1;
    g[rr][cc + 2] = s2; g[rr][cc + 3] = s3;
    __syncthreads();
    int c = tid;
    float a0 = 0.f, a1 = 0.f, a2 = 0.f, a3 = 0.f;
#pragma unroll 4
    for (int i = 0; i < 256; ++i) {
      float wq = b2f(WqT[i * 256 + c]);
      a0 += wq * g[0][i]; a1 += wq * g[1][i];
      a2 += wq * g[2][i]; a3 += wq * g[3][i];
    }
    ushort4 o;
    o.x = f2b(a0); o.y = f2b(a1); o.z = f2b(a2); o.w = f2b(a3);
    *(ushort4*)(T1 + (long)b * 65536 + (long)c * 256 + blockIdx.x * 4) = o;
  } else {
    int t = threadIdx.x;
    const float* rb = r + b * C;
    float su = 0.f, sw = 0.f;
    for (int i = 0; i < C; ++i) {
      float rv = rb[i];
      su += qkv_w[(256 + t) * 256 + i] * rv;
      sw += qkv_w[t * 256 + i] * rv;
    }
    u[b * C + t] = su;
    w[b * C + t] = sw;
  }
}

// ---------------------------------------------------------------------------
// softmax over rows of S -> attn^T bf16 (attnT[d][c] = attn[c][d])
__global__ __launch_bounds__(256) void softmax_kernel(const float* __restrict__ S,
                                                      u16* __restrict__ attnT) {
  int row = blockIdx.x;
  int t = threadIdx.x;
  float v = S[(long)row * C + t];
  __shared__ float red[256];
  red[t] = v; __syncthreads();
  for (int st = 128; st > 0; st >>= 1) {
    if (t < st) red[t] = fmaxf(red[t], red[t + st]);
    __syncthreads();
  }
  float mx = red[0];
  __syncthreads();
  float e = __expf(v - mx);
  red[t] = e; __syncthreads();
  for (int st = 128; st > 0; st >>= 1) {
    if (t < st) red[t] += red[t + st];
    __syncthreads();
  }
  float inv = 1.0f / red[0];
  int b = row >> 8, c = row & 255;
  attnT[(long)b * 65536 + t * 256 + c] = f2b(e * inv);
}

// ---------------------------------------------------------------------------
// Fused conv3x3 implicit-GEMM + attention-output GEMM, BK=64 (proven:
// 104us, MfmaUtil 36%, 0 bank conflicts). 128x128 tile, 4 waves, acc[4][4];
// merged conv+attn accumulator. 10 taps (9 conv + 1 attn) x 4 chunks of 64-K
// = 40 barrier-steps. 2 LDS buffers [128][64] (64KB -> 2 blocks/CU).
// Slot swizzle: LDS[row][slot] holds global slot (slot ^ (row&7)); read
// applies same XOR. Structure notes: per-wave tiles >64x64 spill (r3/r13);
// A-from-global gathers serialize VMEM (r9); BK=32 doesn't raise occupancy
// (r12). This config is the measured optimum of the explored space.
__global__ __launch_bounds__(256, 2) void convattn_kernel(
    const u16* __restrict__ xT, const u16* __restrict__ cw,
    const u16* __restrict__ W2, const u16* __restrict__ zbuf,
    const float* __restrict__ conv_b, const float* __restrict__ cb,
    float* __restrict__ out) {
  int b = blockIdx.y;
  int to = blockIdx.x >> 5;  // 0..1
  int tn = blockIdx.x & 31;  // 0..31
  int row0 = to * 128, col0 = tn * 128;
  const u16* xTb = xT + (long)b * CN;
  const u16* W2b = W2 + (long)b * 65536;

  __shared__ u16 lA[2][8192];   // [128][64] u16 per buffer
  __shared__ u16 lB[2][8192];

  int tid = threadIdx.x;
  int lane = tid & 63, w = tid >> 6;
  int wm = w >> 1, wn = w & 1;
  int fr = lane & 15, kq = lane >> 4;
  int fx = fr & 7;              // == row&7 for all fragment rows

  // staging decomp: each wave stages rows [w*32, w*32+32), 4 instrs of 8 rows
  int lr = lane >> 3, sl = lane & 7;
  int ss = sl ^ lr;             // swizzled source slot (row&7 == lr)

  const u16* aA[4]; const u16* pBt[4]; int hh[4], ww[4];
  const u16* zsrc = zbuf + ss * 8;
#pragma unroll
  for (int i = 0; i < 4; ++i) {
    int r = w * 32 + i * 8 + lr;
    aA[i] = cw + (long)(row0 + r) * 2304 + ss * 8;
    int t = col0 + r;
    hh[i] = t >> 6; ww[i] = t & 63;
    pBt[i] = xTb + (long)t * 256 + ss * 8;
  }
  int nb = col0 >> 8, jb = col0 & 255;

  f32x4 acc[4][4] = {};
  const u16 *at0, *at1, *at2, *at3, *bt0, *bt1, *bt2, *bt3;

  auto set_tap = [&](int tap) {
    int dh = tap / 3 - 1, dw = tap % 3 - 1;
    long sh = (long)(dh * 64 + dw) * 256;
    at0 = aA[0] + tap * 256; at1 = aA[1] + tap * 256;
    at2 = aA[2] + tap * 256; at3 = aA[3] + tap * 256;
    bool v0 = ((unsigned)(hh[0] + dh) < 64u) && ((unsigned)(ww[0] + dw) < 64u);
    bool v1 = ((unsigned)(hh[1] + dh) < 64u) && ((unsigned)(ww[1] + dw) < 64u);
    bool v2 = ((unsigned)(hh[2] + dh) < 64u) && ((unsigned)(ww[2] + dw) < 64u);
    bool v3 = ((unsigned)(hh[3] + dh) < 64u) && ((unsigned)(ww[3] + dw) < 64u);
    bt0 = v0 ? pBt[0] + sh : zsrc;
    bt1 = v1 ? pBt[1] + sh : zsrc;
    bt2 = v2 ? pBt[2] + sh : zsrc;
    bt3 = v3 ? pBt[3] + sh : zsrc;
  };
  auto set_attn = [&]() {
#pragma unroll
    for (int i = 0; i < 4; ++i) {
      int r = w * 32 + i * 8 + lr;
      const u16* a = xTb + (long)((row0 + r) * 16 + nb) * 256 + ss * 8;
      const u16* bb = W2b + (long)(jb + r) * 256 + ss * 8;
      if (i == 0) { at0 = a; bt0 = bb; }
      else if (i == 1) { at1 = a; bt1 = bb; }
      else if (i == 2) { at2 = a; bt2 = bb; }
      else { at3 = a; bt3 = bb; }
    }
  };

  auto STAGE = [&](int buf, int chunk) {
    int k = chunk * 64;
    glds16(at0 + k, &lA[buf][(w * 32 + 0) * 64]);
    glds16(at1 + k, &lA[buf][(w * 32 + 8) * 64]);
    glds16(at2 + k, &lA[buf][(w * 32 + 16) * 64]);
    glds16(at3 + k, &lA[buf][(w * 32 + 24) * 64]);
    glds16(bt0 + k, &lB[buf][(w * 32 + 0) * 64]);
    glds16(bt1 + k, &lB[buf][(w * 32 + 8) * 64]);
    glds16(bt2 + k, &lB[buf][(w * 32 + 16) * 64]);
    glds16(bt3 + k, &lB[buf][(w * 32 + 24) * 64]);
  };
  auto COMPUTE = [&](int buf) {
    bf16x8 af[4][2], bf[4][2];
#pragma unroll
    for (int m = 0; m < 4; ++m) {
      int row = wm * 64 + m * 16 + fr;
#pragma unroll
      for (int kh = 0; kh < 2; ++kh)
        af[m][kh] = *(const bf16x8*)&lA[buf][row * 64 + (((kh << 2) + kq) ^ fx) * 8];
    }
#pragma unroll
    for (int n = 0; n < 4; ++n) {
      int row = wn * 64 + n * 16 + fr;
#pragma unroll
      for (int kh = 0; kh < 2; ++kh)
        bf[n][kh] = *(const bf16x8*)&lB[buf][row * 64 + (((kh << 2) + kq) ^ fx) * 8];
    }
    __builtin_amdgcn_s_setprio(1);
#pragma unroll
    for (int kh = 0; kh < 2; ++kh)
#pragma unroll
      for (int m = 0; m < 4; ++m)
#pragma unroll
        for (int n = 0; n < 4; ++n)
          acc[m][n] = __builtin_amdgcn_mfma_f32_16x16x32_bf16(af[m][kh], bf[n][kh], acc[m][n], 0, 0, 0);
    __builtin_amdgcn_s_setprio(0);
  };

  set_tap(0);
  STAGE(0, 0);
  asm volatile("s_waitcnt vmcnt(0)" ::: "memory");
  __builtin_amdgcn_sched_barrier(0);
  __builtin_amdgcn_s_barrier();
  __builtin_amdgcn_sched_barrier(0);

  int buf = 0;
#pragma unroll 1
  for (int T = 0; T < 10; ++T) {
#pragma unroll
    for (int j = 0; j < 4; ++j) {
      if (!(T == 9 && j == 3)) {
        if (j < 3) {
          STAGE(buf ^ 1, j + 1);
        } else {
          if (T < 8) set_tap(T + 1);
          else set_attn();
          STAGE(buf ^ 1, 0);
        }
      }
      COMPUTE(buf);
      asm volatile("s_waitcnt vmcnt(0)" ::: "memory");
      __builtin_amdgcn_sched_barrier(0);
      __builtin_amdgcn_s_barrier();
      __builtin_amdgcn_sched_barrier(0);
      buf ^= 1;
    }
  }

  float* ob = out + (long)b * CN;
  const float* cbb = cb + b * C;
#pragma unroll
  for (int m = 0; m < 4; ++m) {
    int go = row0 + wm * 64 + m * 16 + kq * 4;
#pragma unroll
    for (int nn = 0; nn < 4; ++nn) {
      int cc = wn * 64 + nn * 16 + fr;
      float cbv = cbb[jb + cc];
#pragma unroll
      for (int r = 0; r < 4; ++r)
        ob[(long)(go + r) * NTOK + col0 + cc] =
            acc[m][nn][r] + conv_b[go + r] + cbv;
    }
  }
}

// ---------------------------------------------------------------------------
extern "C" void kernel_launch(void* const* d_in, const int* in_sizes, int n_in,
                              void* d_out, int out_size, void* d_ws, size_t ws_size,
                              hipStream_t stream) {
  const float* x = (const float*)d_in[0];
  const float* qkv_w = (const float*)d_in[1];
  const float* qkv_b = (const float*)d_in[2];
  const float* proj_w = (const float*)d_in[3];
  const float* proj_b = (const float*)d_in[4];
  const float* conv_w = (const float*)d_in[5];
  const float* conv_b = (const float*)d_in[6];
  float* out = (float*)d_out;
  char* ws = (char*)d_ws;

  u16* xbf = (u16*)(ws);                    // 32 MB
  u16* xT = (u16*)(ws + 33554432);          // 32 MB
  u16* T1bf = (u16*)(ws + 67108864);        // 2 MB (G never materialized)
  u16* Gpart = (u16*)(ws + 69206016);       // 8 bf16 slices x 16 b = 16 MB,
                                            // dead after reduceG_T1
  float* Sf = (float*)(ws + 71303168);      // union w/ Gpart (written after)
  u16* attnT = (u16*)(ws + 75497472);       // union w/ Gpart (written after)
  u16* Mbf = (u16*)(ws + 77594624);         // union w/ Gpart (written after)
  u16* W2bf = (u16*)(ws + 79691776);        // union w/ Gpart (written after)
  u16* WqT = (u16*)(ws + 85983232);
  u16* Wk = (u16*)(ws + 86114304);
  u16* WvT = (u16*)(ws + 86245376);
  u16* Pw = (u16*)(ws + 86376448);
  u16* cw = (u16*)(ws + 86507520);
  float* rws = (float*)(ws + 87687168);
  float* uws = (float*)(ws + 87703552);
  float* wws = (float*)(ws + 87719936);
  float* cb = (float*)(ws + 87736320);
  u16* zbuf = (u16*)(ws + 87752704);

  prep_w_kernel<<<3328, 256, 0, stream>>>(qkv_w, proj_w, conv_w, WqT, Wk, WvT,
                                          Pw, cw, rws, zbuf);
  prep_x_kernel<<<dim3(128, 8, BATCH), 256, 0, stream>>>(x, xbf, xT, rws);

  // G = X*X^T per batch, split-K x8 -> bf16 partials (2 blocks/CU)
  gemm_glds_kernel<5><<<dim3(4, 8, BATCH), 256, 0, stream>>>(
      xbf, xbf, Gpart, 512, 4096, 4096, 256, 2, CN, CN, 65536,
      0.f, nullptr, nullptr, nullptr, nullptr, 0);
  // reduce bf16 split-K partials -> T1 directly (G symmetric) + bias_uw
  reduceG_T1_bias_kernel<<<dim3(65, BATCH), 256, 0, stream>>>(
      Gpart, WqT, T1bf, qkv_w, rws, uws, wws);

  // S = (T1 * Wk^T + bias terms) * scale  (64x64 tiles, 256 blocks)
  gemm64_kernel<2><<<dim3(16, 1, BATCH), 256, 0, stream>>>(
      T1bf, Wk, Sf, 65536, 0, 65536,
      0.0625f, qkv_b, qkv_b + 256, uws, wws, 256);

  softmax_kernel<<<BATCH * C, 256, 0, stream>>>(Sf, attnT);

  // M = Pw * attn   (B operand = attn^T)
  gemm64_kernel<1><<<dim3(16, 1, BATCH), 256, 0, stream>>>(
      Pw, attnT, Mbf, 0, 65536, 65536,
      0.f, nullptr, nullptr, nullptr, nullptr, 0);
  // W2 = M * Wv (B operand = WvT); block 16 per batch computes cbias
  gemm64_kernel<4><<<dim3(17, 1, BATCH), 256, 0, stream>>>(
      Mbf, WvT, W2bf, 65536, 0, 65536,
      0.f, qkv_b, proj_b, nullptr, cb, 256);

  // fused conv + attention-output, single store of out
  convattn_kernel<<<dim3(64, BATCH), 256, 0, stream>>>(xT, cw, W2bf, zbuf,
                                                       conv_b, cb, out);
}

// Round 18
// 204.477 us; speedup vs baseline: 1.0528x; 1.0122x over previous
//
#include <hip/hip_runtime.h>
#include <hip/hip_bf16.h>

typedef unsigned short u16;
typedef __bf16 bf16x8 __attribute__((ext_vector_type(8)));
typedef float f32x4 __attribute__((ext_vector_type(4)));

#define BATCH 16
#define C 256
#define NTOK 4096      // H*W
#define CN 1048576     // C*NTOK

__device__ __forceinline__ u16 f2b(float f) {
  __hip_bfloat16 h = __float2bfloat16(f);
  return __builtin_bit_cast(u16, h);
}
__device__ __forceinline__ float b2f(u16 u) {
  unsigned int x = ((unsigned int)u) << 16;
  return __builtin_bit_cast(float, x);
}

// async global->LDS, 16B per lane. LDS dest must be wave-uniform base
// (HW adds lane*16); global src is per-lane.
__device__ __forceinline__ void glds16(const u16* g, u16* l) {
  __builtin_amdgcn_global_load_lds(
      (const __attribute__((address_space(1))) unsigned int*)(g),
      (__attribute__((address_space(3))) unsigned int*)(l), 16, 0, 0);
}

// ---------------------------------------------------------------------------
// prep (merged): blocks [0,16384) = prep_x (x -> xbf, xT, rws atomics);
// blocks [16384, 19712) = prep_w (weights -> WqT/Wk/WvT/Pw/cw).
// rws and zbuf are zeroed by a hipMemsetAsync before this launch.
__global__ __launch_bounds__(256) void prep_kernel(
    const float* __restrict__ x, const float* __restrict__ qkv_w,
    const float* __restrict__ proj_w, const float* __restrict__ conv_w,
    u16* __restrict__ xbf, u16* __restrict__ xT, float* __restrict__ rws,
    u16* __restrict__ WqT, u16* __restrict__ Wk, u16* __restrict__ WvT,
    u16* __restrict__ Pw, u16* __restrict__ cw) {
  __shared__ float t[32][33];
  int bx = blockIdx.x;
  int tid = threadIdx.x;
  if (bx < 16384) {
    int n0 = (bx & 127) * 32;
    int c0 = ((bx >> 7) & 7) * 32;
    int b = bx >> 10;
    int i = tid >> 3, j4 = (tid & 7) * 4;
    const float* xb = x + (long)b * CN;
    float4 v = *(const float4*)(xb + (long)(c0 + i) * NTOK + n0 + j4);
    ushort4 bv;
    bv.x = f2b(v.x); bv.y = f2b(v.y); bv.z = f2b(v.z); bv.w = f2b(v.w);
    *(ushort4*)(xbf + (long)b * CN + (long)(c0 + i) * NTOK + n0 + j4) = bv;
    t[i][j4 + 0] = v.x; t[i][j4 + 1] = v.y; t[i][j4 + 2] = v.z; t[i][j4 + 3] = v.w;
    __syncthreads();
    ushort4 o;
    o.x = f2b(t[j4 + 0][i]); o.y = f2b(t[j4 + 1][i]);
    o.z = f2b(t[j4 + 2][i]); o.w = f2b(t[j4 + 3][i]);
    *(ushort4*)(xT + (long)b * CN + (long)(n0 + i) * C + c0 + j4) = o;
    if (tid < 32) {
      float s = 0.f;
#pragma unroll
      for (int j = 0; j < 32; ++j) s += t[tid][j];
      atomicAdd(&rws[b * C + c0 + tid], s);
    }
  } else {
    int idx = (bx - 16384) * 256 + tid;
    if (idx < 65536) {
      WqT[(idx & 255) * 256 + (idx >> 8)] = f2b(qkv_w[idx]);
    } else if (idx < 131072) {
      int e = idx - 65536;
      Wk[e] = f2b(qkv_w[65536 + e]);
    } else if (idx < 196608) {
      int e = idx - 131072;
      int i = e >> 8, d = e & 255;
      WvT[e] = f2b(qkv_w[131072 + d * 256 + i]);
    } else if (idx < 262144) {
      int e = idx - 196608;
      Pw[e] = f2b(proj_w[e]);
    } else if (idx < 851968) {
      int e = idx - 262144;
      int o = e / 2304;
      int rem = e - o * 2304;
      int tap = rem >> 8, i = rem & 255;
      cw[e] = f2b(conv_w[o * 2304 + i * 9 + tap]);
    }
  }
}

// ---------------------------------------------------------------------------
// Generic GEMM C = A*B^T, 128x128 tile, BK=32, 4 waves, glds+swizzle.
// EPI 5: bf16 partial store at ((b*gridDim.y)+ks)*sC (split-K slices).
template <int EPI>
__global__ __launch_bounds__(256, 2) void gemm_glds_kernel(
    const u16* __restrict__ A, const u16* __restrict__ B, void* __restrict__ Cv,
    int K, int lda, int ldb, int ldc, int tilesN, long sA, long sB, long sC) {
  int b = blockIdx.z, ks = blockIdx.y;
  A += (long)b * sA + (long)ks * K;
  B += (long)b * sB + (long)ks * K;
  int ty = blockIdx.x / tilesN, tx = blockIdx.x % tilesN;
  int row0 = ty * 128, col0 = tx * 128;

  __shared__ u16 lA[2][4096];
  __shared__ u16 lB[2][4096];

  int tid = threadIdx.x;
  int lane = tid & 63, wv = tid >> 6;
  int wm = wv >> 1, wn = wv & 1;
  int fr = lane & 15, kq = lane >> 4;
  int kqs = kq ^ ((fr >> 1) & 3);

  int c0 = wv * 128 + lane, c1 = c0 + 64;
  int r0s = c0 >> 2, r1s = c1 >> 2;
  int ls0 = (c0 & 3) ^ ((r0s >> 1) & 3);
  int ls1 = (c1 & 3) ^ ((r1s >> 1) & 3);
  const u16* pA0 = A + (long)(row0 + r0s) * lda + ls0 * 8;
  const u16* pA1 = A + (long)(row0 + r1s) * lda + ls1 * 8;
  const u16* pB0 = B + (long)(col0 + r0s) * ldb + ls0 * 8;
  const u16* pB1 = B + (long)(col0 + r1s) * ldb + ls1 * 8;
  int dst0 = wv * 1024, dst1 = wv * 1024 + 512;

  f32x4 acc[4][4] = {};

  auto STAGE = [&](int buf, int t) {
    int k0 = t << 5;
    glds16(pA0 + k0, &lA[buf][dst0]);
    glds16(pA1 + k0, &lA[buf][dst1]);
    glds16(pB0 + k0, &lB[buf][dst0]);
    glds16(pB1 + k0, &lB[buf][dst1]);
  };
  auto COMPUTE = [&](int buf) {
    bf16x8 af[4], bfr[4];
#pragma unroll
    for (int m = 0; m < 4; ++m)
      af[m] = *(const bf16x8*)&lA[buf][(wm * 64 + m * 16 + fr) * 32 + kqs * 8];
#pragma unroll
    for (int n = 0; n < 4; ++n)
      bfr[n] = *(const bf16x8*)&lB[buf][(wn * 64 + n * 16 + fr) * 32 + kqs * 8];
#pragma unroll
    for (int m = 0; m < 4; ++m)
#pragma unroll
      for (int n = 0; n < 4; ++n)
        acc[m][n] = __builtin_amdgcn_mfma_f32_16x16x32_bf16(af[m], bfr[n], acc[m][n], 0, 0, 0);
  };

  int nk = K >> 5, cur = 0;
  STAGE(0, 0);
  __syncthreads();
  for (int t = 0; t < nk; ++t) {
    if (t + 1 < nk) STAGE(cur ^ 1, t + 1);
    COMPUTE(cur);
    __syncthreads();
    cur ^= 1;
  }

  if (EPI == 5) {
    __hip_bfloat16* Cb =
        (__hip_bfloat16*)Cv + ((long)b * gridDim.y + ks) * sC;
#pragma unroll
    for (int m = 0; m < 4; ++m)
#pragma unroll
      for (int n = 0; n < 4; ++n)
#pragma unroll
        for (int r = 0; r < 4; ++r) {
          int gr = row0 + wm * 64 + m * 16 + kq * 4 + r;
          int gc = col0 + wn * 64 + n * 16 + fr;
          Cb[(long)gr * ldc + gc] = __float2bfloat16(acc[m][n][r]);
        }
  }
}

// ---------------------------------------------------------------------------
// Small GEMM C = A*B^T (256x256 per batch), 64x64 tiles, 4 waves, wave=32x32,
// acc[2][2], BK=32, glds+swizzle, dbuf. Grid (16,1,B) (+1 for cbias in EPI 4).
// EPI 1: bf16. EPI 4: bf16 + cbias block at x==16.
template <int EPI>
__global__ __launch_bounds__(256, 2) void gemm64_kernel(
    const u16* __restrict__ A, const u16* __restrict__ B, void* __restrict__ Cv,
    long sA, long sB, long sC, const float* __restrict__ e1,
    const float* __restrict__ e2, const float* __restrict__ e4) {
  if (EPI == 4 && blockIdx.x == 16) {
    // cbias: cb[b][j] = proj_b[j] + sum_d M[b][j][d]*qkv_b[512+d]
    int bb = blockIdx.z, j = threadIdx.x;
    const u16* m = A + (long)bb * sA + (long)j * 256;
    float s = 0.f;
    for (int d = 0; d < 256; ++d) s += b2f(m[d]) * e1[512 + d];
    float* cbout = const_cast<float*>(e4);
    cbout[bb * 256 + j] = e2[j] + s;
    return;
  }
  int b = blockIdx.z;
  A += (long)b * sA;
  B += (long)b * sB;
  int ty = blockIdx.x >> 2, tx = blockIdx.x & 3;
  int row0 = ty * 64, col0 = tx * 64;

  __shared__ u16 lA[2][2048];   // [64][32]
  __shared__ u16 lB[2][2048];

  int tid = threadIdx.x;
  int lane = tid & 63, w = tid >> 6;
  int wm = w >> 1, wn = w & 1;
  int fr = lane & 15, kq = lane >> 4;
  int kqs = kq ^ ((fr >> 1) & 3);

  int rs = tid >> 2;
  int ls = (tid & 3) ^ ((rs >> 1) & 3);
  const u16* pA = A + (long)(row0 + rs) * 256 + ls * 8;
  const u16* pB = B + (long)(col0 + rs) * 256 + ls * 8;
  int dst = w * 512;

  f32x4 acc[2][2] = {};

  auto STAGE = [&](int buf, int t) {
    int k0 = t << 5;
    glds16(pA + k0, &lA[buf][dst]);
    glds16(pB + k0, &lB[buf][dst]);
  };
  auto COMPUTE = [&](int buf) {
    bf16x8 af[2], bfr[2];
#pragma unroll
    for (int m = 0; m < 2; ++m)
      af[m] = *(const bf16x8*)&lA[buf][(wm * 32 + m * 16 + fr) * 32 + kqs * 8];
#pragma unroll
    for (int n = 0; n < 2; ++n)
      bfr[n] = *(const bf16x8*)&lB[buf][(wn * 32 + n * 16 + fr) * 32 + kqs * 8];
#pragma unroll
    for (int m = 0; m < 2; ++m)
#pragma unroll
      for (int n = 0; n < 2; ++n)
        acc[m][n] = __builtin_amdgcn_mfma_f32_16x16x32_bf16(af[m], bfr[n], acc[m][n], 0, 0, 0);
  };

  int cur = 0;
  STAGE(0, 0);
  __syncthreads();
  for (int t = 0; t < 8; ++t) {
    if (t + 1 < 8) STAGE(cur ^ 1, t + 1);
    COMPUTE(cur);
    __syncthreads();
    cur ^= 1;
  }

  __hip_bfloat16* Cb = (__hip_bfloat16*)Cv + (long)b * sC;
#pragma unroll
  for (int m = 0; m < 2; ++m)
#pragma unroll
    for (int n = 0; n < 2; ++n)
#pragma unroll
      for (int r = 0; r < 4; ++r) {
        int gr = row0 + wm * 32 + m * 16 + kq * 4 + r;
        int gc = col0 + wn * 32 + n * 16 + fr;
        Cb[(long)gr * 256 + gc] = __float2bfloat16(acc[m][n][r]);
      }
}

// ---------------------------------------------------------------------------
// Fused S GEMM + row-softmax -> attnT. Block = 32 S-rows x 256 cols so every
// row is block-local; grid (8, B) = 128 blocks. 4 waves, wave w owns cols
// [w*64, w*64+64) (acc[2][4]). S = (T1*Wk^T + bias)*scale computed into
// padded LDS sf[32][257] (f32), then two-phase row max / exp-sum, then
// thread-per-column writes attnT[d][c] (transposed) directly.
__global__ __launch_bounds__(256, 2) void s_softmax_kernel(
    const u16* __restrict__ T1, const u16* __restrict__ Wk,
    u16* __restrict__ attnT, const float* __restrict__ qkv_b,
    const float* __restrict__ uws, const float* __restrict__ wws) {
  int b = blockIdx.y;
  int r0 = blockIdx.x * 32;
  const u16* Ab = T1 + (long)b * 65536 + (long)r0 * 256;

  __shared__ u16 lA[2][1024];     // [32][32]
  __shared__ u16 lB[2][8192];     // [256][32]
  __shared__ float sf[32][257];   // +1 pad: conflict-free column reads
  __shared__ float red[32][8];
  __shared__ float rmax[32], rinv[32];

  int tid = threadIdx.x;
  int lane = tid & 63, w = tid >> 6;
  int fr = lane & 15, kq = lane >> 4;
  int kqs = kq ^ ((fr >> 1) & 3);

  // A staging (waves 0,1): rows tid>>2 (0..31)
  int rsA = tid >> 2;
  int lsA = (tid & 3) ^ ((rsA >> 1) & 3);
  const u16* pA = Ab + (long)rsA * 256 + lsA * 8;
  // B staging: wave w stages rows w*64 + i*16 + (lane>>2), i=0..3
  int lrB = lane >> 2;
  int lsB = (lane & 3) ^ ((lrB >> 1) & 3);
  const u16* pB = Wk + (long)(w * 64 + lrB) * 256 + lsB * 8;

  f32x4 acc[2][4] = {};

  auto STAGE = [&](int buf, int t) {
    int k0 = t << 5;
    if (w == 0) glds16(pA + k0, &lA[buf][0]);
    if (w == 1) glds16(pA + k0, &lA[buf][512]);
    glds16(pB + k0, &lB[buf][(w * 64 + 0) * 32]);
    glds16(pB + 16 * 256 + k0, &lB[buf][(w * 64 + 16) * 32]);
    glds16(pB + 32 * 256 + k0, &lB[buf][(w * 64 + 32) * 32]);
    glds16(pB + 48 * 256 + k0, &lB[buf][(w * 64 + 48) * 32]);
  };
  auto COMPUTE = [&](int buf) {
    bf16x8 af[2], bfr[4];
#pragma unroll
    for (int m = 0; m < 2; ++m)
      af[m] = *(const bf16x8*)&lA[buf][(m * 16 + fr) * 32 + kqs * 8];
#pragma unroll
    for (int n = 0; n < 4; ++n)
      bfr[n] = *(const bf16x8*)&lB[buf][(w * 64 + n * 16 + fr) * 32 + kqs * 8];
#pragma unroll
    for (int m = 0; m < 2; ++m)
#pragma unroll
      for (int n = 0; n < 4; ++n)
        acc[m][n] = __builtin_amdgcn_mfma_f32_16x16x32_bf16(af[m], bfr[n], acc[m][n], 0, 0, 0);
  };

  int cur = 0;
  STAGE(0, 0);
  __syncthreads();
  for (int t = 0; t < 8; ++t) {
    if (t + 1 < 8) STAGE(cur ^ 1, t + 1);
    COMPUTE(cur);
    __syncthreads();
    cur ^= 1;
  }

  // epilogue: bias terms + scale into sf
  const float* ub = uws + b * 256;
  const float* wb = wws + b * 256;
#pragma unroll
  for (int m = 0; m < 2; ++m)
#pragma unroll
    for (int n = 0; n < 4; ++n)
#pragma unroll
      for (int r = 0; r < 4; ++r) {
        int row = m * 16 + kq * 4 + r;
        int col = w * 64 + n * 16 + fr;
        float qb = qkv_b[r0 + row];
        float v = acc[m][n][r] + qb * ub[col] + qkv_b[256 + col] * wb[r0 + row] +
                  4096.0f * qb * qkv_b[256 + col];
        sf[row][col] = v * 0.0625f;
      }
  __syncthreads();

  // row max (8 segments of 32 per row)
  int rr = tid >> 3, sg = (tid & 7) * 32;
  float mx = -3.4e38f;
  for (int c2 = sg; c2 < sg + 32; ++c2) mx = fmaxf(mx, sf[rr][c2]);
  red[rr][tid & 7] = mx;
  __syncthreads();
  if (tid < 32) {
    float m2 = red[tid][0];
#pragma unroll
    for (int k = 1; k < 8; ++k) m2 = fmaxf(m2, red[tid][k]);
    rmax[tid] = m2;
  }
  __syncthreads();
  // exp + row sum
  float m2 = rmax[rr], sm = 0.f;
  for (int c2 = sg; c2 < sg + 32; ++c2) {
    float e = __expf(sf[rr][c2] - m2);
    sf[rr][c2] = e;
    sm += e;
  }
  red[rr][tid & 7] = sm;
  __syncthreads();
  if (tid < 32) {
    float s2 = red[tid][0];
#pragma unroll
    for (int k = 1; k < 8; ++k) s2 += red[tid][k];
    rinv[tid] = 1.0f / s2;
  }
  __syncthreads();
  // write attnT[d=col][c=row]: thread = column, 32 contiguous u16 per thread
  int c = tid;
  u16* aT = attnT + (long)b * 65536 + (long)c * 256 + r0;
#pragma unroll 8
  for (int r = 0; r < 32; ++r) aT[r] = f2b(sf[r][c] * rinv[r]);
}

// ---------------------------------------------------------------------------
// reduceG + T1 + bias_uw merged. grid (65, B). Partials are bf16 (8 slices).
__global__ __launch_bounds__(256) void reduceG_T1_bias_kernel(
    const u16* __restrict__ Gp, const u16* __restrict__ WqT,
    u16* __restrict__ T1, const float* __restrict__ qkv_w,
    const float* __restrict__ r, float* __restrict__ u, float* __restrict__ w) {
  int b = blockIdx.y;
  if (blockIdx.x < 64) {
    __shared__ float g[4][256];
    int tid = threadIdx.x;
    int e = blockIdx.x * 1024 + tid * 4;
    const u16* base = Gp + (long)b * 8 * 65536;
    float s0 = 0.f, s1 = 0.f, s2 = 0.f, s3 = 0.f;
#pragma unroll
    for (int sl = 0; sl < 8; ++sl) {
      ushort4 v = *(const ushort4*)(base + (long)sl * 65536 + e);
      s0 += b2f(v.x); s1 += b2f(v.y); s2 += b2f(v.z); s3 += b2f(v.w);
    }
    int rr = tid >> 6, cc = (tid & 63) * 4;
    g[rr][cc + 0] = s0; g[rr][cc + 1] = s1;
    g[rr][cc + 2] = s2; g[rr][cc + 3] = s3;
    __syncthreads();
    int c = tid;
    float a0 = 0.f, a1 = 0.f, a2 = 0.f, a3 = 0.f;
#pragma unroll 4
    for (int i = 0; i < 256; ++i) {
      float wq = b2f(WqT[i * 256 + c]);
      a0 += wq * g[0][i]; a1 += wq * g[1][i];
      a2 += wq * g[2][i]; a3 += wq * g[3][i];
    }
    ushort4 o;
    o.x = f2b(a0); o.y = f2b(a1); o.z = f2b(a2); o.w = f2b(a3);
    *(ushort4*)(T1 + (long)b * 65536 + (long)c * 256 + blockIdx.x * 4) = o;
  } else {
    int t = threadIdx.x;
    const float* rb = r + b * C;
    float su = 0.f, sw = 0.f;
    for (int i = 0; i < C; ++i) {
      float rv = rb[i];
      su += qkv_w[(256 + t) * 256 + i] * rv;
      sw += qkv_w[t * 256 + i] * rv;
    }
    u[b * C + t] = su;
    w[b * C + t] = sw;
  }
}

// ---------------------------------------------------------------------------
// Fused conv3x3 implicit-GEMM + attention-output GEMM, BK=64 (proven:
// 104us, MfmaUtil 36%, 0 bank conflicts). 128x128 tile, 4 waves, acc[4][4];
// merged conv+attn accumulator. 10 taps (9 conv + 1 attn) x 4 chunks of 64-K
// = 40 barrier-steps. 2 LDS buffers [128][64] (64KB -> 2 blocks/CU).
// Slot swizzle: LDS[row][slot] holds global slot (slot ^ (row&7)); read
// applies same XOR. Structure notes: per-wave tiles >64x64 spill (r3/r13);
// A-from-global gathers serialize VMEM (r9); BK=32 doesn't raise occupancy
// (r12). This config is the measured optimum of the explored space.
__global__ __launch_bounds__(256, 2) void convattn_kernel(
    const u16* __restrict__ xT, const u16* __restrict__ cw,
    const u16* __restrict__ W2, const u16* __restrict__ zbuf,
    const float* __restrict__ conv_b, const float* __restrict__ cb,
    float* __restrict__ out) {
  int b = blockIdx.y;
  int to = blockIdx.x >> 5;  // 0..1
  int tn = blockIdx.x & 31;  // 0..31
  int row0 = to * 128, col0 = tn * 128;
  const u16* xTb = xT + (long)b * CN;
  const u16* W2b = W2 + (long)b * 65536;

  __shared__ u16 lA[2][8192];   // [128][64] u16 per buffer
  __shared__ u16 lB[2][8192];

  int tid = threadIdx.x;
  int lane = tid & 63, w = tid >> 6;
  int wm = w >> 1, wn = w & 1;
  int fr = lane & 15, kq = lane >> 4;
  int fx = fr & 7;              // == row&7 for all fragment rows

  // staging decomp: each wave stages rows [w*32, w*32+32), 4 instrs of 8 rows
  int lr = lane >> 3, sl = lane & 7;
  int ss = sl ^ lr;             // swizzled source slot (row&7 == lr)

  const u16* aA[4]; const u16* pBt[4]; int hh[4], ww[4];
  const u16* zsrc = zbuf + ss * 8;
#pragma unroll
  for (int i = 0; i < 4; ++i) {
    int r = w * 32 + i * 8 + lr;
    aA[i] = cw + (long)(row0 + r) * 2304 + ss * 8;
    int t = col0 + r;
    hh[i] = t >> 6; ww[i] = t & 63;
    pBt[i] = xTb + (long)t * 256 + ss * 8;
  }
  int nb = col0 >> 8, jb = col0 & 255;

  f32x4 acc[4][4] = {};
  const u16 *at0, *at1, *at2, *at3, *bt0, *bt1, *bt2, *bt3;

  auto set_tap = [&](int tap) {
    int dh = tap / 3 - 1, dw = tap % 3 - 1;
    long sh = (long)(dh * 64 + dw) * 256;
    at0 = aA[0] + tap * 256; at1 = aA[1] + tap * 256;
    at2 = aA[2] + tap * 256; at3 = aA[3] + tap * 256;
    bool v0 = ((unsigned)(hh[0] + dh) < 64u) && ((unsigned)(ww[0] + dw) < 64u);
    bool v1 = ((unsigned)(hh[1] + dh) < 64u) && ((unsigned)(ww[1] + dw) < 64u);
    bool v2 = ((unsigned)(hh[2] + dh) < 64u) && ((unsigned)(ww[2] + dw) < 64u);
    bool v3 = ((unsigned)(hh[3] + dh) < 64u) && ((unsigned)(ww[3] + dw) < 64u);
    bt0 = v0 ? pBt[0] + sh : zsrc;
    bt1 = v1 ? pBt[1] + sh : zsrc;
    bt2 = v2 ? pBt[2] + sh : zsrc;
    bt3 = v3 ? pBt[3] + sh : zsrc;
  };
  auto set_attn = [&]() {
#pragma unroll
    for (int i = 0; i < 4; ++i) {
      int r = w * 32 + i * 8 + lr;
      const u16* a = xTb + (long)((row0 + r) * 16 + nb) * 256 + ss * 8;
      const u16* bb = W2b + (long)(jb + r) * 256 + ss * 8;
      if (i == 0) { at0 = a; bt0 = bb; }
      else if (i == 1) { at1 = a; bt1 = bb; }
      else if (i == 2) { at2 = a; bt2 = bb; }
      else { at3 = a; bt3 = bb; }
    }
  };

  auto STAGE = [&](int buf, int chunk) {
    int k = chunk * 64;
    glds16(at0 + k, &lA[buf][(w * 32 + 0) * 64]);
    glds16(at1 + k, &lA[buf][(w * 32 + 8) * 64]);
    glds16(at2 + k, &lA[buf][(w * 32 + 16) * 64]);
    glds16(at3 + k, &lA[buf][(w * 32 + 24) * 64]);
    glds16(bt0 + k, &lB[buf][(w * 32 + 0) * 64]);
    glds16(bt1 + k, &lB[buf][(w * 32 + 8) * 64]);
    glds16(bt2 + k, &lB[buf][(w * 32 + 16) * 64]);
    glds16(bt3 + k, &lB[buf][(w * 32 + 24) * 64]);
  };
  auto COMPUTE = [&](int buf) {
    bf16x8 af[4][2], bf[4][2];
#pragma unroll
    for (int m = 0; m < 4; ++m) {
      int row = wm * 64 + m * 16 + fr;
#pragma unroll
      for (int kh = 0; kh < 2; ++kh)
        af[m][kh] = *(const bf16x8*)&lA[buf][row * 64 + (((kh << 2) + kq) ^ fx) * 8];
    }
#pragma unroll
    for (int n = 0; n < 4; ++n) {
      int row = wn * 64 + n * 16 + fr;
#pragma unroll
      for (int kh = 0; kh < 2; ++kh)
        bf[n][kh] = *(const bf16x8*)&lB[buf][row * 64 + (((kh << 2) + kq) ^ fx) * 8];
    }
    __builtin_amdgcn_s_setprio(1);
#pragma unroll
    for (int kh = 0; kh < 2; ++kh)
#pragma unroll
      for (int m = 0; m < 4; ++m)
#pragma unroll
        for (int n = 0; n < 4; ++n)
          acc[m][n] = __builtin_amdgcn_mfma_f32_16x16x32_bf16(af[m][kh], bf[n][kh], acc[m][n], 0, 0, 0);
    __builtin_amdgcn_s_setprio(0);
  };

  set_tap(0);
  STAGE(0, 0);
  asm volatile("s_waitcnt vmcnt(0)" ::: "memory");
  __builtin_amdgcn_sched_barrier(0);
  __builtin_amdgcn_s_barrier();
  __builtin_amdgcn_sched_barrier(0);

  int buf = 0;
#pragma unroll 1
  for (int T = 0; T < 10; ++T) {
#pragma unroll
    for (int j = 0; j < 4; ++j) {
      if (!(T == 9 && j == 3)) {
        if (j < 3) {
          STAGE(buf ^ 1, j + 1);
        } else {
          if (T < 8) set_tap(T + 1);
          else set_attn();
          STAGE(buf ^ 1, 0);
        }
      }
      COMPUTE(buf);
      asm volatile("s_waitcnt vmcnt(0)" ::: "memory");
      __builtin_amdgcn_sched_barrier(0);
      __builtin_amdgcn_s_barrier();
      __builtin_amdgcn_sched_barrier(0);
      buf ^= 1;
    }
  }

  float* ob = out + (long)b * CN;
  const float* cbb = cb + b * C;
#pragma unroll
  for (int m = 0; m < 4; ++m) {
    int go = row0 + wm * 64 + m * 16 + kq * 4;
#pragma unroll
    for (int nn = 0; nn < 4; ++nn) {
      int cc = wn * 64 + nn * 16 + fr;
      float cbv = cbb[jb + cc];
#pragma unroll
      for (int r = 0; r < 4; ++r)
        ob[(long)(go + r) * NTOK + col0 + cc] =
            acc[m][nn][r] + conv_b[go + r] + cbv;
    }
  }
}

// ---------------------------------------------------------------------------
extern "C" void kernel_launch(void* const* d_in, const int* in_sizes, int n_in,
                              void* d_out, int out_size, void* d_ws, size_t ws_size,
                              hipStream_t stream) {
  const float* x = (const float*)d_in[0];
  const float* qkv_w = (const float*)d_in[1];
  const float* qkv_b = (const float*)d_in[2];
  const float* proj_w = (const float*)d_in[3];
  const float* proj_b = (const float*)d_in[4];
  const float* conv_w = (const float*)d_in[5];
  const float* conv_b = (const float*)d_in[6];
  float* out = (float*)d_out;
  char* ws = (char*)d_ws;

  u16* xbf = (u16*)(ws);                    // 32 MB
  u16* xT = (u16*)(ws + 33554432);          // 32 MB
  u16* T1bf = (u16*)(ws + 67108864);        // 2 MB (G never materialized)
  u16* Gpart = (u16*)(ws + 69206016);       // 8 bf16 slices x 16 b = 16 MB,
                                            // dead after reduceG_T1
  u16* attnT = (u16*)(ws + 75497472);       // union w/ Gpart (written after)
  u16* Mbf = (u16*)(ws + 77594624);         // union w/ Gpart (written after)
  u16* W2bf = (u16*)(ws + 79691776);        // union w/ Gpart (written after)
  u16* WqT = (u16*)(ws + 85983232);
  u16* Wk = (u16*)(ws + 86114304);
  u16* WvT = (u16*)(ws + 86245376);
  u16* Pw = (u16*)(ws + 86376448);
  u16* cw = (u16*)(ws + 86507520);
  float* rws = (float*)(ws + 87687168);     // 16 KB, memset-zeroed
  u16* zbuf = (u16*)(ws + 87703552);        // 512 B, memset-zeroed (adjacent)
  float* uws = (float*)(ws + 87704064);
  float* wws = (float*)(ws + 87720448);
  float* cb = (float*)(ws + 87736832);

  // zero rws (atomics target) + zbuf (conv halo source) in one memset
  hipMemsetAsync(ws + 87687168, 0, 16896, stream);

  // merged prep: prep_x (16384 blocks) + prep_w (3328 blocks)
  prep_kernel<<<19712, 256, 0, stream>>>(x, qkv_w, proj_w, conv_w, xbf, xT,
                                         rws, WqT, Wk, WvT, Pw, cw);

  // G = X*X^T per batch, split-K x8 -> bf16 partials (2 blocks/CU)
  gemm_glds_kernel<5><<<dim3(4, 8, BATCH), 256, 0, stream>>>(
      xbf, xbf, Gpart, 512, 4096, 4096, 256, 2, CN, CN, 65536);
  // reduce bf16 split-K partials -> T1 directly (G symmetric) + bias_uw
  reduceG_T1_bias_kernel<<<dim3(65, BATCH), 256, 0, stream>>>(
      Gpart, WqT, T1bf, qkv_w, rws, uws, wws);

  // S = (T1*Wk^T + bias)*scale, fused row-softmax -> attnT (transposed)
  s_softmax_kernel<<<dim3(8, BATCH), 256, 0, stream>>>(
      T1bf, Wk, attnT, qkv_b, uws, wws);

  // M = Pw * attn   (B operand = attn^T)
  gemm64_kernel<1><<<dim3(16, 1, BATCH), 256, 0, stream>>>(
      Pw, attnT, Mbf, 0, 65536, 65536, nullptr, nullptr, nullptr);
  // W2 = M * Wv (B operand = WvT); block 16 per batch computes cbias
  gemm64_kernel<4><<<dim3(17, 1, BATCH), 256, 0, stream>>>(
      Mbf, WvT, W2bf, 65536, 0, 65536, qkv_b, proj_b, cb);

  // fused conv + attention-output, single store of out
  convattn_kernel<<<dim3(64, BATCH), 256, 0, stream>>>(xT, cw, W2bf, zbuf,
                                                       conv_b, cb, out);
}

// Round 19
// 203.313 us; speedup vs baseline: 1.0589x; 1.0057x over previous
//
#include <hip/hip_runtime.h>
#include <hip/hip_bf16.h>

typedef unsigned short u16;
typedef __bf16 bf16x8 __attribute__((ext_vector_type(8)));
typedef float f32x4 __attribute__((ext_vector_type(4)));

#define BATCH 16
#define C 256
#define NTOK 4096      // H*W
#define CN 1048576     // C*NTOK

__device__ __forceinline__ u16 f2b(float f) {
  __hip_bfloat16 h = __float2bfloat16(f);
  return __builtin_bit_cast(u16, h);
}
__device__ __forceinline__ float b2f(u16 u) {
  unsigned int x = ((unsigned int)u) << 16;
  return __builtin_bit_cast(float, x);
}

// async global->LDS, 16B per lane. LDS dest must be wave-uniform base
// (HW adds lane*16); global src is per-lane.
__device__ __forceinline__ void glds16(const u16* g, u16* l) {
  __builtin_amdgcn_global_load_lds(
      (const __attribute__((address_space(1))) unsigned int*)(g),
      (__attribute__((address_space(3))) unsigned int*)(l), 16, 0, 0);
}

// ---------------------------------------------------------------------------
// prep (merged): blocks [0,16384) = prep_x (x -> xbf, xT, rws atomics);
// blocks [16384, 19712) = prep_w (weights -> WqT/Wk/WvT/Pw/cw).
// rws and zbuf are zeroed by a hipMemsetAsync before this launch.
__global__ __launch_bounds__(256) void prep_kernel(
    const float* __restrict__ x, const float* __restrict__ qkv_w,
    const float* __restrict__ proj_w, const float* __restrict__ conv_w,
    u16* __restrict__ xbf, u16* __restrict__ xT, float* __restrict__ rws,
    u16* __restrict__ WqT, u16* __restrict__ Wk, u16* __restrict__ WvT,
    u16* __restrict__ Pw, u16* __restrict__ cw) {
  __shared__ float t[32][33];
  int bx = blockIdx.x;
  int tid = threadIdx.x;
  if (bx < 16384) {
    int n0 = (bx & 127) * 32;
    int c0 = ((bx >> 7) & 7) * 32;
    int b = bx >> 10;
    int i = tid >> 3, j4 = (tid & 7) * 4;
    const float* xb = x + (long)b * CN;
    float4 v = *(const float4*)(xb + (long)(c0 + i) * NTOK + n0 + j4);
    ushort4 bv;
    bv.x = f2b(v.x); bv.y = f2b(v.y); bv.z = f2b(v.z); bv.w = f2b(v.w);
    *(ushort4*)(xbf + (long)b * CN + (long)(c0 + i) * NTOK + n0 + j4) = bv;
    t[i][j4 + 0] = v.x; t[i][j4 + 1] = v.y; t[i][j4 + 2] = v.z; t[i][j4 + 3] = v.w;
    __syncthreads();
    ushort4 o;
    o.x = f2b(t[j4 + 0][i]); o.y = f2b(t[j4 + 1][i]);
    o.z = f2b(t[j4 + 2][i]); o.w = f2b(t[j4 + 3][i]);
    *(ushort4*)(xT + (long)b * CN + (long)(n0 + i) * C + c0 + j4) = o;
    if (tid < 32) {
      float s = 0.f;
#pragma unroll
      for (int j = 0; j < 32; ++j) s += t[tid][j];
      atomicAdd(&rws[b * C + c0 + tid], s);
    }
  } else {
    int idx = (bx - 16384) * 256 + tid;
    if (idx < 65536) {
      WqT[(idx & 255) * 256 + (idx >> 8)] = f2b(qkv_w[idx]);
    } else if (idx < 131072) {
      int e = idx - 65536;
      Wk[e] = f2b(qkv_w[65536 + e]);
    } else if (idx < 196608) {
      int e = idx - 131072;
      int i = e >> 8, d = e & 255;
      WvT[e] = f2b(qkv_w[131072 + d * 256 + i]);
    } else if (idx < 262144) {
      int e = idx - 196608;
      Pw[e] = f2b(proj_w[e]);
    } else if (idx < 851968) {
      int e = idx - 262144;
      int o = e / 2304;
      int rem = e - o * 2304;
      int tap = rem >> 8, i = rem & 255;
      cw[e] = f2b(conv_w[o * 2304 + i * 9 + tap]);
    }
  }
}

// ---------------------------------------------------------------------------
// Generic GEMM C = A*B^T, 128x128 tile, BK=32, 4 waves, glds+swizzle.
// EPI 5: bf16 partial store at ((b*gridDim.y)+ks)*sC (split-K slices).
template <int EPI>
__global__ __launch_bounds__(256, 2) void gemm_glds_kernel(
    const u16* __restrict__ A, const u16* __restrict__ B, void* __restrict__ Cv,
    int K, int lda, int ldb, int ldc, int tilesN, long sA, long sB, long sC) {
  int b = blockIdx.z, ks = blockIdx.y;
  A += (long)b * sA + (long)ks * K;
  B += (long)b * sB + (long)ks * K;
  int ty = blockIdx.x / tilesN, tx = blockIdx.x % tilesN;
  int row0 = ty * 128, col0 = tx * 128;

  __shared__ u16 lA[2][4096];
  __shared__ u16 lB[2][4096];

  int tid = threadIdx.x;
  int lane = tid & 63, wv = tid >> 6;
  int wm = wv >> 1, wn = wv & 1;
  int fr = lane & 15, kq = lane >> 4;
  int kqs = kq ^ ((fr >> 1) & 3);

  int c0 = wv * 128 + lane, c1 = c0 + 64;
  int r0s = c0 >> 2, r1s = c1 >> 2;
  int ls0 = (c0 & 3) ^ ((r0s >> 1) & 3);
  int ls1 = (c1 & 3) ^ ((r1s >> 1) & 3);
  const u16* pA0 = A + (long)(row0 + r0s) * lda + ls0 * 8;
  const u16* pA1 = A + (long)(row0 + r1s) * lda + ls1 * 8;
  const u16* pB0 = B + (long)(col0 + r0s) * ldb + ls0 * 8;
  const u16* pB1 = B + (long)(col0 + r1s) * ldb + ls1 * 8;
  int dst0 = wv * 1024, dst1 = wv * 1024 + 512;

  f32x4 acc[4][4] = {};

  auto STAGE = [&](int buf, int t) {
    int k0 = t << 5;
    glds16(pA0 + k0, &lA[buf][dst0]);
    glds16(pA1 + k0, &lA[buf][dst1]);
    glds16(pB0 + k0, &lB[buf][dst0]);
    glds16(pB1 + k0, &lB[buf][dst1]);
  };
  auto COMPUTE = [&](int buf) {
    bf16x8 af[4], bfr[4];
#pragma unroll
    for (int m = 0; m < 4; ++m)
      af[m] = *(const bf16x8*)&lA[buf][(wm * 64 + m * 16 + fr) * 32 + kqs * 8];
#pragma unroll
    for (int n = 0; n < 4; ++n)
      bfr[n] = *(const bf16x8*)&lB[buf][(wn * 64 + n * 16 + fr) * 32 + kqs * 8];
#pragma unroll
    for (int m = 0; m < 4; ++m)
#pragma unroll
      for (int n = 0; n < 4; ++n)
        acc[m][n] = __builtin_amdgcn_mfma_f32_16x16x32_bf16(af[m], bfr[n], acc[m][n], 0, 0, 0);
  };

  int nk = K >> 5, cur = 0;
  STAGE(0, 0);
  __syncthreads();
  for (int t = 0; t < nk; ++t) {
    if (t + 1 < nk) STAGE(cur ^ 1, t + 1);
    COMPUTE(cur);
    __syncthreads();
    cur ^= 1;
  }

  if (EPI == 5) {
    __hip_bfloat16* Cb =
        (__hip_bfloat16*)Cv + ((long)b * gridDim.y + ks) * sC;
#pragma unroll
    for (int m = 0; m < 4; ++m)
#pragma unroll
      for (int n = 0; n < 4; ++n)
#pragma unroll
        for (int r = 0; r < 4; ++r) {
          int gr = row0 + wm * 64 + m * 16 + kq * 4 + r;
          int gc = col0 + wn * 64 + n * 16 + fr;
          Cb[(long)gr * ldc + gc] = __float2bfloat16(acc[m][n][r]);
        }
  }
}

// ---------------------------------------------------------------------------
// Fused M = Pw*attn (B-op attnT), cbias, W2 = M*Wv (B-op WvT): W2 row j and
// cbias[j] depend only on M row j, so a block owning full M rows finishes
// them without a global round-trip (M never hits HBM).
// Grid (4, B): block = M rows [r0, r0+64) x 256 cols; 4 waves x 64-col
// strips, acc[4][4]. Phase-1 M-tile -> LDS mts[64][264] (stride 264 u16:
// phase-2 A-frag reads put 8 consecutive lanes on 8 disjoint 4-bank runs;
// 528B row pitch keeps 16B alignment). B staging = proven gemm64 involution.
__global__ __launch_bounds__(256, 2) void mw2_kernel(
    const u16* __restrict__ Pw, const u16* __restrict__ attnT,
    const u16* __restrict__ WvT, u16* __restrict__ W2,
    const float* __restrict__ qkv_b, const float* __restrict__ proj_b,
    float* __restrict__ cb) {
  int b = blockIdx.y;
  int r0 = blockIdx.x * 64;
  const u16* aTb = attnT + (long)b * 65536;

  __shared__ u16 lA[2][2048];     // [64][32]
  __shared__ u16 lB[2][8192];     // [256][32]
  __shared__ u16 mts[64][264];    // M tile, bf16
  __shared__ float cred[64][4];

  int tid = threadIdx.x;
  int lane = tid & 63, w = tid >> 6;
  int fr = lane & 15, kq = lane >> 4;
  int kqs = kq ^ ((fr >> 1) & 3);

  // A staging (64 rows): row tid>>2, swizzled slot
  int rsA = tid >> 2;
  int lsA = (tid & 3) ^ ((rsA >> 1) & 3);
  const u16* pA = Pw + (long)(r0 + rsA) * 256 + lsA * 8;
  // B staging: wave w rows w*64 + i*16 + (lane>>2)
  int lrB = lane >> 2;
  int lsB = (lane & 3) ^ ((lrB >> 1) & 3);
  long boff = (long)(w * 64 + lrB) * 256 + lsB * 8;

  f32x4 acc[4][4] = {};

  auto STAGE = [&](const u16* Bsrc, int buf, int t) {
    int k0 = t << 5;
    glds16(pA + k0, &lA[buf][w * 512]);
#pragma unroll
    for (int i = 0; i < 4; ++i)
      glds16(Bsrc + boff + i * 4096 + k0, &lB[buf][(w * 64 + i * 16) * 32]);
  };
  auto COMPUTE1 = [&](int buf) {
    bf16x8 af[4], bfr[4];
#pragma unroll
    for (int m = 0; m < 4; ++m)
      af[m] = *(const bf16x8*)&lA[buf][(m * 16 + fr) * 32 + kqs * 8];
#pragma unroll
    for (int n = 0; n < 4; ++n)
      bfr[n] = *(const bf16x8*)&lB[buf][(w * 64 + n * 16 + fr) * 32 + kqs * 8];
#pragma unroll
    for (int m = 0; m < 4; ++m)
#pragma unroll
      for (int n = 0; n < 4; ++n)
        acc[m][n] = __builtin_amdgcn_mfma_f32_16x16x32_bf16(af[m], bfr[n], acc[m][n], 0, 0, 0);
  };

  // ---- phase 1: M = Pw * attn ----
  int cur = 0;
  STAGE(aTb, 0, 0);
  __syncthreads();
  for (int t = 0; t < 8; ++t) {
    if (t + 1 < 8) STAGE(aTb, cur ^ 1, t + 1);
    COMPUTE1(cur);
    __syncthreads();
    cur ^= 1;
  }
  // M tile -> LDS (bf16, same rounding as the old global Mbf path)
#pragma unroll
  for (int m = 0; m < 4; ++m)
#pragma unroll
    for (int n = 0; n < 4; ++n)
#pragma unroll
      for (int r = 0; r < 4; ++r)
        mts[m * 16 + kq * 4 + r][w * 64 + n * 16 + fr] = f2b(acc[m][n][r]);
  __syncthreads();

  // prefetch W2 phase step 0 while computing cbias partials
  cur = 0;
  STAGE(WvT, 0, 0);
  {
    int j = tid >> 2, q = tid & 3;
    float s = 0.f;
    int d0 = q * 64;
#pragma unroll 8
    for (int d = d0; d < d0 + 64; ++d) s += b2f(mts[j][d]) * qkv_b[512 + d];
    cred[j][q] = s;
  }
  __syncthreads();     // cred visible; stage-0 loads drained
  if (tid < 64)
    cb[b * 256 + r0 + tid] = proj_b[r0 + tid] +
        cred[tid][0] + cred[tid][1] + cred[tid][2] + cred[tid][3];

  // ---- phase 2: W2 = M * Wv ----
#pragma unroll
  for (int m = 0; m < 4; ++m)
#pragma unroll
    for (int n = 0; n < 4; ++n)
      acc[m][n] = f32x4{0.f, 0.f, 0.f, 0.f};
  for (int t = 0; t < 8; ++t) {
    if (t + 1 < 8) STAGE(WvT, cur ^ 1, t + 1);
    bf16x8 af[4], bfr[4];
#pragma unroll
    for (int m = 0; m < 4; ++m)
      af[m] = *(const bf16x8*)&mts[m * 16 + fr][t * 32 + kq * 8];
#pragma unroll
    for (int n = 0; n < 4; ++n)
      bfr[n] = *(const bf16x8*)&lB[cur][(w * 64 + n * 16 + fr) * 32 + kqs * 8];
#pragma unroll
    for (int m = 0; m < 4; ++m)
#pragma unroll
      for (int n = 0; n < 4; ++n)
        acc[m][n] = __builtin_amdgcn_mfma_f32_16x16x32_bf16(af[m], bfr[n], acc[m][n], 0, 0, 0);
    __syncthreads();
    cur ^= 1;
  }

  __hip_bfloat16* W2b = (__hip_bfloat16*)W2 + (long)b * 65536;
#pragma unroll
  for (int m = 0; m < 4; ++m)
#pragma unroll
    for (int n = 0; n < 4; ++n)
#pragma unroll
      for (int r = 0; r < 4; ++r) {
        int gr = r0 + m * 16 + kq * 4 + r;
        int gc = w * 64 + n * 16 + fr;
        W2b[(long)gr * 256 + gc] = __float2bfloat16(acc[m][n][r]);
      }
}

// ---------------------------------------------------------------------------
// Fused S GEMM + row-softmax -> attnT. Block = 32 S-rows x 256 cols so every
// row is block-local; grid (8, B) = 128 blocks. 4 waves, wave w owns cols
// [w*64, w*64+64) (acc[2][4]). S = (T1*Wk^T + bias)*scale computed into
// padded LDS sf[32][257] (f32), then two-phase row max / exp-sum, then
// thread-per-column writes attnT[d][c] (transposed) directly.
__global__ __launch_bounds__(256, 2) void s_softmax_kernel(
    const u16* __restrict__ T1, const u16* __restrict__ Wk,
    u16* __restrict__ attnT, const float* __restrict__ qkv_b,
    const float* __restrict__ uws, const float* __restrict__ wws) {
  int b = blockIdx.y;
  int r0 = blockIdx.x * 32;
  const u16* Ab = T1 + (long)b * 65536 + (long)r0 * 256;

  __shared__ u16 lA[2][1024];     // [32][32]
  __shared__ u16 lB[2][8192];     // [256][32]
  __shared__ float sf[32][257];   // +1 pad: conflict-free column reads
  __shared__ float red[32][8];
  __shared__ float rmax[32], rinv[32];

  int tid = threadIdx.x;
  int lane = tid & 63, w = tid >> 6;
  int fr = lane & 15, kq = lane >> 4;
  int kqs = kq ^ ((fr >> 1) & 3);

  // A staging (waves 0,1): rows tid>>2 (0..31)
  int rsA = tid >> 2;
  int lsA = (tid & 3) ^ ((rsA >> 1) & 3);
  const u16* pA = Ab + (long)rsA * 256 + lsA * 8;
  // B staging: wave w stages rows w*64 + i*16 + (lane>>2), i=0..3
  int lrB = lane >> 2;
  int lsB = (lane & 3) ^ ((lrB >> 1) & 3);
  const u16* pB = Wk + (long)(w * 64 + lrB) * 256 + lsB * 8;

  f32x4 acc[2][4] = {};

  auto STAGE = [&](int buf, int t) {
    int k0 = t << 5;
    if (w == 0) glds16(pA + k0, &lA[buf][0]);
    if (w == 1) glds16(pA + k0, &lA[buf][512]);
    glds16(pB + k0, &lB[buf][(w * 64 + 0) * 32]);
    glds16(pB + 16 * 256 + k0, &lB[buf][(w * 64 + 16) * 32]);
    glds16(pB + 32 * 256 + k0, &lB[buf][(w * 64 + 32) * 32]);
    glds16(pB + 48 * 256 + k0, &lB[buf][(w * 64 + 48) * 32]);
  };
  auto COMPUTE = [&](int buf) {
    bf16x8 af[2], bfr[4];
#pragma unroll
    for (int m = 0; m < 2; ++m)
      af[m] = *(const bf16x8*)&lA[buf][(m * 16 + fr) * 32 + kqs * 8];
#pragma unroll
    for (int n = 0; n < 4; ++n)
      bfr[n] = *(const bf16x8*)&lB[buf][(w * 64 + n * 16 + fr) * 32 + kqs * 8];
#pragma unroll
    for (int m = 0; m < 2; ++m)
#pragma unroll
      for (int n = 0; n < 4; ++n)
        acc[m][n] = __builtin_amdgcn_mfma_f32_16x16x32_bf16(af[m], bfr[n], acc[m][n], 0, 0, 0);
  };

  int cur = 0;
  STAGE(0, 0);
  __syncthreads();
  for (int t = 0; t < 8; ++t) {
    if (t + 1 < 8) STAGE(cur ^ 1, t + 1);
    COMPUTE(cur);
    __syncthreads();
    cur ^= 1;
  }

  // epilogue: bias terms + scale into sf
  const float* ub = uws + b * 256;
  const float* wb = wws + b * 256;
#pragma unroll
  for (int m = 0; m < 2; ++m)
#pragma unroll
    for (int n = 0; n < 4; ++n)
#pragma unroll
      for (int r = 0; r < 4; ++r) {
        int row = m * 16 + kq * 4 + r;
        int col = w * 64 + n * 16 + fr;
        float qb = qkv_b[r0 + row];
        float v = acc[m][n][r] + qb * ub[col] + qkv_b[256 + col] * wb[r0 + row] +
                  4096.0f * qb * qkv_b[256 + col];
        sf[row][col] = v * 0.0625f;
      }
  __syncthreads();

  // row max (8 segments of 32 per row)
  int rr = tid >> 3, sg = (tid & 7) * 32;
  float mx = -3.4e38f;
  for (int c2 = sg; c2 < sg + 32; ++c2) mx = fmaxf(mx, sf[rr][c2]);
  red[rr][tid & 7] = mx;
  __syncthreads();
  if (tid < 32) {
    float m2 = red[tid][0];
#pragma unroll
    for (int k = 1; k < 8; ++k) m2 = fmaxf(m2, red[tid][k]);
    rmax[tid] = m2;
  }
  __syncthreads();
  // exp + row sum
  float m2 = rmax[rr], sm = 0.f;
  for (int c2 = sg; c2 < sg + 32; ++c2) {
    float e = __expf(sf[rr][c2] - m2);
    sf[rr][c2] = e;
    sm += e;
  }
  red[rr][tid & 7] = sm;
  __syncthreads();
  if (tid < 32) {
    float s2 = red[tid][0];
#pragma unroll
    for (int k = 1; k < 8; ++k) s2 += red[tid][k];
    rinv[tid] = 1.0f / s2;
  }
  __syncthreads();
  // write attnT[d=col][c=row]: thread = column, 32 contiguous u16 per thread
  int c = tid;
  u16* aT = attnT + (long)b * 65536 + (long)c * 256 + r0;
#pragma unroll 8
  for (int r = 0; r < 32; ++r) aT[r] = f2b(sf[r][c] * rinv[r]);
}

// ---------------------------------------------------------------------------
// reduceG + T1 + bias_uw merged. grid (65, B). Partials are bf16 (8 slices).
__global__ __launch_bounds__(256) void reduceG_T1_bias_kernel(
    const u16* __restrict__ Gp, const u16* __restrict__ WqT,
    u16* __restrict__ T1, const float* __restrict__ qkv_w,
    const float* __restrict__ r, float* __restrict__ u, float* __restrict__ w) {
  int b = blockIdx.y;
  if (blockIdx.x < 64) {
    __shared__ float g[4][256];
    int tid = threadIdx.x;
    int e = blockIdx.x * 1024 + tid * 4;
    const u16* base = Gp + (long)b * 8 * 65536;
    float s0 = 0.f, s1 = 0.f, s2 = 0.f, s3 = 0.f;
#pragma unroll
    for (int sl = 0; sl < 8; ++sl) {
      ushort4 v = *(const ushort4*)(base + (long)sl * 65536 + e);
      s0 += b2f(v.x); s1 += b2f(v.y); s2 += b2f(v.z); s3 += b2f(v.w);
    }
    int rr = tid >> 6, cc = (tid & 63) * 4;
    g[rr][cc + 0] = s0; g[rr][cc + 1] = s1;
    g[rr][cc + 2] = s2; g[rr][cc + 3] = s3;
    __syncthreads();
    int c = tid;
    float a0 = 0.f, a1 = 0.f, a2 = 0.f, a3 = 0.f;
#pragma unroll 4
    for (int i = 0; i < 256; ++i) {
      float wq = b2f(WqT[i * 256 + c]);
      a0 += wq * g[0][i]; a1 += wq * g[1][i];
      a2 += wq * g[2][i]; a3 += wq * g[3][i];
    }
    ushort4 o;
    o.x = f2b(a0); o.y = f2b(a1); o.z = f2b(a2); o.w = f2b(a3);
    *(ushort4*)(T1 + (long)b * 65536 + (long)c * 256 + blockIdx.x * 4) = o;
  } else {
    int t = threadIdx.x;
    const float* rb = r + b * C;
    float su = 0.f, sw = 0.f;
    for (int i = 0; i < C; ++i) {
      float rv = rb[i];
      su += qkv_w[(256 + t) * 256 + i] * rv;
      sw += qkv_w[t * 256 + i] * rv;
    }
    u[b * C + t] = su;
    w[b * C + t] = sw;
  }
}

// ---------------------------------------------------------------------------
// Fused conv3x3 implicit-GEMM + attention-output GEMM, BK=64 (proven:
// 104us, MfmaUtil 36%, 0 bank conflicts). 128x128 tile, 4 waves, acc[4][4];
// merged conv+attn accumulator. 10 taps (9 conv + 1 attn) x 4 chunks of 64-K
// = 40 barrier-steps. 2 LDS buffers [128][64] (64KB -> 2 blocks/CU).
// Slot swizzle: LDS[row][slot] holds global slot (slot ^ (row&7)); read
// applies same XOR. Structure notes: per-wave tiles >64x64 spill (r3/r13);
// A-from-global gathers serialize VMEM (r9); BK=32 doesn't raise occupancy
// (r12). This config is the measured optimum of the explored space.
__global__ __launch_bounds__(256, 2) void convattn_kernel(
    const u16* __restrict__ xT, const u16* __restrict__ cw,
    const u16* __restrict__ W2, const u16* __restrict__ zbuf,
    const float* __restrict__ conv_b, const float* __restrict__ cb,
    float* __restrict__ out) {
  int b = blockIdx.y;
  int to = blockIdx.x >> 5;  // 0..1
  int tn = blockIdx.x & 31;  // 0..31
  int row0 = to * 128, col0 = tn * 128;
  const u16* xTb = xT + (long)b * CN;
  const u16* W2b = W2 + (long)b * 65536;

  __shared__ u16 lA[2][8192];   // [128][64] u16 per buffer
  __shared__ u16 lB[2][8192];

  int tid = threadIdx.x;
  int lane = tid & 63, w = tid >> 6;
  int wm = w >> 1, wn = w & 1;
  int fr = lane & 15, kq = lane >> 4;
  int fx = fr & 7;              // == row&7 for all fragment rows

  // staging decomp: each wave stages rows [w*32, w*32+32), 4 instrs of 8 rows
  int lr = lane >> 3, sl = lane & 7;
  int ss = sl ^ lr;             // swizzled source slot (row&7 == lr)

  const u16* aA[4]; const u16* pBt[4]; int hh[4], ww[4];
  const u16* zsrc = zbuf + ss * 8;
#pragma unroll
  for (int i = 0; i < 4; ++i) {
    int r = w * 32 + i * 8 + lr;
    aA[i] = cw + (long)(row0 + r) * 2304 + ss * 8;
    int t = col0 + r;
    hh[i] = t >> 6; ww[i] = t & 63;
    pBt[i] = xTb + (long)t * 256 + ss * 8;
  }
  int nb = col0 >> 8, jb = col0 & 255;

  f32x4 acc[4][4] = {};
  const u16 *at0, *at1, *at2, *at3, *bt0, *bt1, *bt2, *bt3;

  auto set_tap = [&](int tap) {
    int dh = tap / 3 - 1, dw = tap % 3 - 1;
    long sh = (long)(dh * 64 + dw) * 256;
    at0 = aA[0] + tap * 256; at1 = aA[1] + tap * 256;
    at2 = aA[2] + tap * 256; at3 = aA[3] + tap * 256;
    bool v0 = ((unsigned)(hh[0] + dh) < 64u) && ((unsigned)(ww[0] + dw) < 64u);
    bool v1 = ((unsigned)(hh[1] + dh) < 64u) && ((unsigned)(ww[1] + dw) < 64u);
    bool v2 = ((unsigned)(hh[2] + dh) < 64u) && ((unsigned)(ww[2] + dw) < 64u);
    bool v3 = ((unsigned)(hh[3] + dh) < 64u) && ((unsigned)(ww[3] + dw) < 64u);
    bt0 = v0 ? pBt[0] + sh : zsrc;
    bt1 = v1 ? pBt[1] + sh : zsrc;
    bt2 = v2 ? pBt[2] + sh : zsrc;
    bt3 = v3 ? pBt[3] + sh : zsrc;
  };
  auto set_attn = [&]() {
#pragma unroll
    for (int i = 0; i < 4; ++i) {
      int r = w * 32 + i * 8 + lr;
      const u16* a = xTb + (long)((row0 + r) * 16 + nb) * 256 + ss * 8;
      const u16* bb = W2b + (long)(jb + r) * 256 + ss * 8;
      if (i == 0) { at0 = a; bt0 = bb; }
      else if (i == 1) { at1 = a; bt1 = bb; }
      else if (i == 2) { at2 = a; bt2 = bb; }
      else { at3 = a; bt3 = bb; }
    }
  };

  auto STAGE = [&](int buf, int chunk) {
    int k = chunk * 64;
    glds16(at0 + k, &lA[buf][(w * 32 + 0) * 64]);
    glds16(at1 + k, &lA[buf][(w * 32 + 8) * 64]);
    glds16(at2 + k, &lA[buf][(w * 32 + 16) * 64]);
    glds16(at3 + k, &lA[buf][(w * 32 + 24) * 64]);
    glds16(bt0 + k, &lB[buf][(w * 32 + 0) * 64]);
    glds16(bt1 + k, &lB[buf][(w * 32 + 8) * 64]);
    glds16(bt2 + k, &lB[buf][(w * 32 + 16) * 64]);
    glds16(bt3 + k, &lB[buf][(w * 32 + 24) * 64]);
  };
  auto COMPUTE = [&](int buf) {
    bf16x8 af[4][2], bf[4][2];
#pragma unroll
    for (int m = 0; m < 4; ++m) {
      int row = wm * 64 + m * 16 + fr;
#pragma unroll
      for (int kh = 0; kh < 2; ++kh)
        af[m][kh] = *(const bf16x8*)&lA[buf][row * 64 + (((kh << 2) + kq) ^ fx) * 8];
    }
#pragma unroll
    for (int n = 0; n < 4; ++n) {
      int row = wn * 64 + n * 16 + fr;
#pragma unroll
      for (int kh = 0; kh < 2; ++kh)
        bf[n][kh] = *(const bf16x8*)&lB[buf][row * 64 + (((kh << 2) + kq) ^ fx) * 8];
    }
    __builtin_amdgcn_s_setprio(1);
#pragma unroll
    for (int kh = 0; kh < 2; ++kh)
#pragma unroll
      for (int m = 0; m < 4; ++m)
#pragma unroll
        for (int n = 0; n < 4; ++n)
          acc[m][n] = __builtin_amdgcn_mfma_f32_16x16x32_bf16(af[m][kh], bf[n][kh], acc[m][n], 0, 0, 0);
    __builtin_amdgcn_s_setprio(0);
  };

  set_tap(0);
  STAGE(0, 0);
  asm volatile("s_waitcnt vmcnt(0)" ::: "memory");
  __builtin_amdgcn_sched_barrier(0);
  __builtin_amdgcn_s_barrier();
  __builtin_amdgcn_sched_barrier(0);

  int buf = 0;
#pragma unroll 1
  for (int T = 0; T < 10; ++T) {
#pragma unroll
    for (int j = 0; j < 4; ++j) {
      if (!(T == 9 && j == 3)) {
        if (j < 3) {
          STAGE(buf ^ 1, j + 1);
        } else {
          if (T < 8) set_tap(T + 1);
          else set_attn();
          STAGE(buf ^ 1, 0);
        }
      }
      COMPUTE(buf);
      asm volatile("s_waitcnt vmcnt(0)" ::: "memory");
      __builtin_amdgcn_sched_barrier(0);
      __builtin_amdgcn_s_barrier();
      __builtin_amdgcn_sched_barrier(0);
      buf ^= 1;
    }
  }

  float* ob = out + (long)b * CN;
  const float* cbb = cb + b * C;
#pragma unroll
  for (int m = 0; m < 4; ++m) {
    int go = row0 + wm * 64 + m * 16 + kq * 4;
#pragma unroll
    for (int nn = 0; nn < 4; ++nn) {
      int cc = wn * 64 + nn * 16 + fr;
      float cbv = cbb[jb + cc];
#pragma unroll
      for (int r = 0; r < 4; ++r)
        ob[(long)(go + r) * NTOK + col0 + cc] =
            acc[m][nn][r] + conv_b[go + r] + cbv;
    }
  }
}

// ---------------------------------------------------------------------------
extern "C" void kernel_launch(void* const* d_in, const int* in_sizes, int n_in,
                              void* d_out, int out_size, void* d_ws, size_t ws_size,
                              hipStream_t stream) {
  const float* x = (const float*)d_in[0];
  const float* qkv_w = (const float*)d_in[1];
  const float* qkv_b = (const float*)d_in[2];
  const float* proj_w = (const float*)d_in[3];
  const float* proj_b = (const float*)d_in[4];
  const float* conv_w = (const float*)d_in[5];
  const float* conv_b = (const float*)d_in[6];
  float* out = (float*)d_out;
  char* ws = (char*)d_ws;

  u16* xbf = (u16*)(ws);                    // 32 MB
  u16* xT = (u16*)(ws + 33554432);          // 32 MB
  u16* T1bf = (u16*)(ws + 67108864);        // 2 MB (G never materialized)
  u16* Gpart = (u16*)(ws + 69206016);       // 8 bf16 slices x 16 b = 16 MB,
                                            // dead after reduceG_T1
  u16* attnT = (u16*)(ws + 75497472);       // union w/ Gpart (written after)
  u16* W2bf = (u16*)(ws + 79691776);        // union w/ Gpart (written after)
  u16* WqT = (u16*)(ws + 85983232);
  u16* Wk = (u16*)(ws + 86114304);
  u16* WvT = (u16*)(ws + 86245376);
  u16* Pw = (u16*)(ws + 86376448);
  u16* cw = (u16*)(ws + 86507520);
  float* rws = (float*)(ws + 87687168);     // 16 KB, memset-zeroed
  u16* zbuf = (u16*)(ws + 87703552);        // 512 B, memset-zeroed (adjacent)
  float* uws = (float*)(ws + 87704064);
  float* wws = (float*)(ws + 87720448);
  float* cb = (float*)(ws + 87736832);

  // zero rws (atomics target) + zbuf (conv halo source) in one memset
  hipMemsetAsync(ws + 87687168, 0, 16896, stream);

  // merged prep: prep_x (16384 blocks) + prep_w (3328 blocks)
  prep_kernel<<<19712, 256, 0, stream>>>(x, qkv_w, proj_w, conv_w, xbf, xT,
                                         rws, WqT, Wk, WvT, Pw, cw);

  // G = X*X^T per batch, split-K x8 -> bf16 partials (2 blocks/CU)
  gemm_glds_kernel<5><<<dim3(4, 8, BATCH), 256, 0, stream>>>(
      xbf, xbf, Gpart, 512, 4096, 4096, 256, 2, CN, CN, 65536);
  // reduce bf16 split-K partials -> T1 directly (G symmetric) + bias_uw
  reduceG_T1_bias_kernel<<<dim3(65, BATCH), 256, 0, stream>>>(
      Gpart, WqT, T1bf, qkv_w, rws, uws, wws);

  // S = (T1*Wk^T + bias)*scale, fused row-softmax -> attnT (transposed)
  s_softmax_kernel<<<dim3(8, BATCH), 256, 0, stream>>>(
      T1bf, Wk, attnT, qkv_b, uws, wws);

  // M = Pw*attn + cbias + W2 = M*Wv, all row-local in one kernel
  mw2_kernel<<<dim3(4, BATCH), 256, 0, stream>>>(
      Pw, attnT, WvT, W2bf, qkv_b, proj_b, cb);

  // fused conv + attention-output, single store of out
  convattn_kernel<<<dim3(64, BATCH), 256, 0, stream>>>(xT, cw, W2bf, zbuf,
                                                       conv_b, cb, out);
}